// Round 2
// baseline (604.373 us; speedup 1.0000x reference)
//
#include <hip/hip_runtime.h>

#define BB 4
#define TT 2048
#define CC 1024
#define HH 4
#define DD 256
#define MM (BB*TT)

#define EPSV 1e-5f
#define NEGBIG (-1e30f)
#define SCALEV 0.0625f   // 1/sqrt(256)

typedef unsigned short u16;
typedef unsigned int   u32;
typedef __bf16 bf16x8 __attribute__((ext_vector_type(8)));
typedef float  f32x4  __attribute__((ext_vector_type(4)));

typedef u32 __attribute__((address_space(1))) gu32;
typedef u32 __attribute__((address_space(3))) lu32;

__device__ __forceinline__ u16 f2bf(float f){
  u32 u = __builtin_bit_cast(u32, f);
  u32 r = (u + 0x7fffu + ((u >> 16) & 1u)) >> 16;
  return (u16)r;
}
__device__ __forceinline__ float bf2f(u16 h){
  u32 u = ((u32)h) << 16;
  return __builtin_bit_cast(float, u);
}
__device__ __forceinline__ void gload_lds16(const u16* g, u16* l){
  __builtin_amdgcn_global_load_lds((const gu32*)g, (lu32*)l, 16, 0, 0);
}

// ---------------- weight f32 -> bf16 ----------------
__global__ __launch_bounds__(256) void conv_w_kernel(
    const float* __restrict__ w0, const float* __restrict__ w1, const float* __restrict__ w2,
    const float* __restrict__ w3, const float* __restrict__ w4, const float* __restrict__ w5,
    u16* __restrict__ o0, u16* __restrict__ o1, u16* __restrict__ o2,
    u16* __restrict__ o3, u16* __restrict__ o4, u16* __restrict__ o5){
  const int i = (blockIdx.x * 256 + threadIdx.x) * 4;
  const float* wsrc[6] = {w0,w1,w2,w3,w4,w5};
  u16* odst[6] = {o0,o1,o2,o3,o4,o5};
#pragma unroll
  for (int k = 0; k < 6; ++k){
    float4 v = *(const float4*)(wsrc[k] + i);
    ushort4 p; p.x=f2bf(v.x); p.y=f2bf(v.y); p.z=f2bf(v.z); p.w=f2bf(v.w);
    *(ushort4*)(odst[k] + i) = p;
  }
}

// ---------------- channel LayerNorm over C per (b,t) row ----------------
template<int OUTBF>
__global__ __launch_bounds__(256) void ln_rows(const float* __restrict__ x,
    const float* __restrict__ g, const float* __restrict__ be, void* __restrict__ out){
  const int row = blockIdx.x, tid = threadIdx.x;
  const float4 v = ((const float4*)(x + (size_t)row * CC))[tid];
  float s  = v.x + v.y + v.z + v.w;
  float ss = v.x*v.x + v.y*v.y + v.z*v.z + v.w*v.w;
  __shared__ float sb[8];
#pragma unroll
  for (int o = 1; o < 64; o <<= 1){ s += __shfl_xor(s, o); ss += __shfl_xor(ss, o); }
  const int wid = tid >> 6, lane = tid & 63;
  if (lane == 0){ sb[wid] = s; sb[4 + wid] = ss; }
  __syncthreads();
  s  = sb[0] + sb[1] + sb[2] + sb[3];
  ss = sb[4] + sb[5] + sb[6] + sb[7];
  const float mu = s * (1.0f / CC);
  const float rstd = rsqrtf(ss * (1.0f / CC) - mu * mu + EPSV);
  const float4 gg = ((const float4*)g)[tid];
  const float4 bb = ((const float4*)be)[tid];
  const float r0 = (v.x - mu) * rstd * gg.x + bb.x;
  const float r1 = (v.y - mu) * rstd * gg.y + bb.y;
  const float r2 = (v.z - mu) * rstd * gg.z + bb.z;
  const float r3 = (v.w - mu) * rstd * gg.w + bb.w;
  if (OUTBF){
    ushort4 p; p.x=f2bf(r0); p.y=f2bf(r1); p.z=f2bf(r2); p.w=f2bf(r3);
    *(ushort4*)((u16*)out + (size_t)row * CC + tid * 4) = p;
  } else {
    ((float4*)((float*)out + (size_t)row * CC))[tid] = make_float4(r0, r1, r2, r3);
  }
}

// ------------ fused q/k/v: dwconv3 (pad1) * mask -> LN -> bf16 ------------
__global__ __launch_bounds__(256) void qkv_pre(const float* __restrict__ h,
    const int* __restrict__ mask,
    const float* __restrict__ qw, const float* __restrict__ kw, const float* __restrict__ vw,
    const float* __restrict__ qg, const float* __restrict__ qb2,
    const float* __restrict__ kg, const float* __restrict__ kb2,
    const float* __restrict__ vg, const float* __restrict__ vb2,
    u16* __restrict__ qn, u16* __restrict__ kn, u16* __restrict__ vn){
  const int row = blockIdx.x, tid = threadIdx.x;
  const int t = row & (TT - 1);
  const float mf = mask[row] ? 1.f : 0.f;
  const float4 z4 = make_float4(0.f, 0.f, 0.f, 0.f);
  const float4 x0 = ((const float4*)(h + (size_t)row * CC))[tid];
  const float4 xm = (t > 0)      ? ((const float4*)(h + (size_t)(row - 1) * CC))[tid] : z4;
  const float4 xp = (t < TT - 1) ? ((const float4*)(h + (size_t)(row + 1) * CC))[tid] : z4;
  const int c = tid * 4;
  const float am[4] = {xm.x, xm.y, xm.z, xm.w};
  const float a0[4] = {x0.x, x0.y, x0.z, x0.w};
  const float ap[4] = {xp.x, xp.y, xp.z, xp.w};
  float yq[4], yk[4], yv[4];
  float sq=0.f, ssq=0.f, sk=0.f, ssk=0.f, sv=0.f, ssv=0.f;
#pragma unroll
  for (int i = 0; i < 4; ++i){
    const float* qwp = qw + (c + i) * 3;
    const float* kwp = kw + (c + i) * 3;
    const float* vwp = vw + (c + i) * 3;
    const float q_ = (am[i]*qwp[0] + a0[i]*qwp[1] + ap[i]*qwp[2]) * mf;
    const float k_ = (am[i]*kwp[0] + a0[i]*kwp[1] + ap[i]*kwp[2]) * mf;
    const float v_ = (am[i]*vwp[0] + a0[i]*vwp[1] + ap[i]*vwp[2]) * mf;
    yq[i]=q_; yk[i]=k_; yv[i]=v_;
    sq+=q_; ssq+=q_*q_; sk+=k_; ssk+=k_*k_; sv+=v_; ssv+=v_*v_;
  }
  __shared__ float sb[24];
#pragma unroll
  for (int o = 1; o < 64; o <<= 1){
    sq += __shfl_xor(sq, o); ssq += __shfl_xor(ssq, o);
    sk += __shfl_xor(sk, o); ssk += __shfl_xor(ssk, o);
    sv += __shfl_xor(sv, o); ssv += __shfl_xor(ssv, o);
  }
  const int wid = tid >> 6, lane = tid & 63;
  if (lane == 0){
    sb[wid]=sq; sb[4+wid]=ssq; sb[8+wid]=sk; sb[12+wid]=ssk; sb[16+wid]=sv; sb[20+wid]=ssv;
  }
  __syncthreads();
  sq  = sb[0]+sb[1]+sb[2]+sb[3];    ssq = sb[4]+sb[5]+sb[6]+sb[7];
  sk  = sb[8]+sb[9]+sb[10]+sb[11];  ssk = sb[12]+sb[13]+sb[14]+sb[15];
  sv  = sb[16]+sb[17]+sb[18]+sb[19];ssv = sb[20]+sb[21]+sb[22]+sb[23];
  {
    const float mu = sq * (1.f/CC), rstd = rsqrtf(ssq*(1.f/CC) - mu*mu + EPSV);
    ushort4 p;
    p.x = f2bf((yq[0]-mu)*rstd*qg[c+0] + qb2[c+0]);
    p.y = f2bf((yq[1]-mu)*rstd*qg[c+1] + qb2[c+1]);
    p.z = f2bf((yq[2]-mu)*rstd*qg[c+2] + qb2[c+2]);
    p.w = f2bf((yq[3]-mu)*rstd*qg[c+3] + qb2[c+3]);
    *(ushort4*)(qn + (size_t)row * CC + c) = p;
  }
  {
    const float mu = sk * (1.f/CC), rstd = rsqrtf(ssk*(1.f/CC) - mu*mu + EPSV);
    ushort4 p;
    p.x = f2bf((yk[0]-mu)*rstd*kg[c+0] + kb2[c+0]);
    p.y = f2bf((yk[1]-mu)*rstd*kg[c+1] + kb2[c+1]);
    p.z = f2bf((yk[2]-mu)*rstd*kg[c+2] + kb2[c+2]);
    p.w = f2bf((yk[3]-mu)*rstd*kg[c+3] + kb2[c+3]);
    *(ushort4*)(kn + (size_t)row * CC + c) = p;
  }
  {
    const float mu = sv * (1.f/CC), rstd = rsqrtf(ssv*(1.f/CC) - mu*mu + EPSV);
    ushort4 p;
    p.x = f2bf((yv[0]-mu)*rstd*vg[c+0] + vb2[c+0]);
    p.y = f2bf((yv[1]-mu)*rstd*vg[c+1] + vb2[c+1]);
    p.z = f2bf((yv[2]-mu)*rstd*vg[c+2] + vb2[c+2]);
    p.w = f2bf((yv[3]-mu)*rstd*vg[c+3] + vb2[c+3]);
    *(ushort4*)(vn + (size_t)row * CC + c) = p;
  }
}

// ---------------- bf16 "bt" GEMM: C[m,n] = sum_k A[m,k]*W[n,k] + bias[n] ----------------
// MODE 0: out bf16 (M,C).  MODE 1: out f32 = (acc+bias)*mask[m] + resid[m,n].
// MODE 2: out f32 = acc+bias+resid.  MODE 3: out bf16 in (B,H,D,T) transposed layout.
template<int MODE>
__global__ __launch_bounds__(256) void gemm_bt(
    const u16* __restrict__ A, const u16* __restrict__ Bw,
    const float* __restrict__ bias, void* __restrict__ out,
    const float* __restrict__ resid, const int* __restrict__ mask){
  __shared__ u16 As[128 * 32];
  __shared__ u16 Bs[128 * 32];
  const int tid = threadIdx.x, lane = tid & 63, wid = tid >> 6;
  const int wr = wid >> 1, wc = wid & 1;
  const int bm = blockIdx.x, bn = blockIdx.y;
  f32x4 acc[4][4];
#pragma unroll
  for (int i = 0; i < 4; ++i)
#pragma unroll
    for (int j = 0; j < 4; ++j) acc[i][j] = (f32x4){0.f, 0.f, 0.f, 0.f};
  const u16* gA = A  + (size_t)(bm * 128 + wid * 32 + (lane >> 2)) * CC + (lane & 3) * 8;
  const u16* gB = Bw + (size_t)(bn * 128 + wid * 32 + (lane >> 2)) * CC + (lane & 3) * 8;
  u16* lA = &As[wid * 1024];
  u16* lB = &Bs[wid * 1024];
  const int la = lane & 15, lg8 = (lane >> 4) * 8;
  for (int kt = 0; kt < CC / 32; ++kt){
    gload_lds16(gA + kt * 32, lA);
    gload_lds16(gA + kt * 32 + (size_t)16 * CC, lA + 512);
    gload_lds16(gB + kt * 32, lB);
    gload_lds16(gB + kt * 32 + (size_t)16 * CC, lB + 512);
    __syncthreads();
    bf16x8 af[4], bf[4];
#pragma unroll
    for (int mi = 0; mi < 4; ++mi) af[mi] = *(const bf16x8*)&As[(wr*64 + mi*16 + la)*32 + lg8];
#pragma unroll
    for (int ni = 0; ni < 4; ++ni) bf[ni] = *(const bf16x8*)&Bs[(wc*64 + ni*16 + la)*32 + lg8];
#pragma unroll
    for (int mi = 0; mi < 4; ++mi)
#pragma unroll
      for (int ni = 0; ni < 4; ++ni)
        acc[mi][ni] = __builtin_amdgcn_mfma_f32_16x16x32_bf16(af[mi], bf[ni], acc[mi][ni], 0, 0, 0);
    __syncthreads();
  }
  const int lg = lane >> 4;
#pragma unroll
  for (int mi = 0; mi < 4; ++mi){
    const int mb = bm * 128 + wr * 64 + mi * 16 + lg * 4;
#pragma unroll
    for (int ni = 0; ni < 4; ++ni){
      const int n = bn * 128 + wc * 64 + ni * 16 + la;
      const float bz = bias[n];
      if (MODE == 0){
        u16* o = (u16*)out;
#pragma unroll
        for (int j = 0; j < 4; ++j) o[(size_t)(mb + j) * CC + n] = f2bf(acc[mi][ni][j] + bz);
      } else if (MODE == 1){
        float* o = (float*)out;
#pragma unroll
        for (int j = 0; j < 4; ++j){
          const int m = mb + j;
          const float mf = mask[m] ? 1.f : 0.f;
          o[(size_t)m * CC + n] = (acc[mi][ni][j] + bz) * mf + resid[(size_t)m * CC + n];
        }
      } else if (MODE == 2){
        float* o = (float*)out;
#pragma unroll
        for (int j = 0; j < 4; ++j){
          const int m = mb + j;
          o[(size_t)m * CC + n] = acc[mi][ni][j] + bz + resid[(size_t)m * CC + n];
        }
      } else {
        u16* o = (u16*)out;
        const int bq = mb >> 11, tq = mb & (TT - 1);
        const int hq = n >> 8, dq = n & 255;
        ushort4 p;
        p.x = f2bf(acc[mi][ni][0] + bz); p.y = f2bf(acc[mi][ni][1] + bz);
        p.z = f2bf(acc[mi][ni][2] + bz); p.w = f2bf(acc[mi][ni][3] + bz);
        *(ushort4*)&o[(size_t)((bq * HH + hq) * DD + dq) * TT + tq] = p;
      }
    }
  }
}

// ---------------- flash attention: per block one (b,h) x 64 q-rows ----------------
// Q,K in (B*T, C) bf16; V pre-transposed to (B,H,D,T) bf16. Online softmax in f32.
// Computes O^T = V^T * P^T via mfma (both operand frags are contiguous 16B reads).
__global__ __launch_bounds__(256) void flash_attn(
    const u16* __restrict__ Q, const u16* __restrict__ Kg,
    const u16* __restrict__ Vt, const int* __restrict__ mask,
    u16* __restrict__ Oa){
  __shared__ u16 Ks[32 * 264];      // 32 k-rows x (256+8)
  __shared__ u16 Vs[256 * 40];      // 256 d-rows x (32+8)
  __shared__ u16 Ps[4 * 16 * 40];   // per-wave P: 16 q x (32+8)
  const int qt = blockIdx.x, bh = blockIdx.y;
  const int b = bh >> 2, h2 = bh & 3;
  const int tid = threadIdx.x, lane = tid & 63, wid = tid >> 6;
  const int la = lane & 15, lg = lane >> 4;
  bf16x8 qf[8];
  const u16* qrow = Q + (size_t)(b * TT + qt * 64 + wid * 16 + la) * CC + h2 * DD + lg * 8;
#pragma unroll
  for (int kd = 0; kd < 8; ++kd) qf[kd] = *(const bf16x8*)(qrow + kd * 32);
  f32x4 oacc[16];
#pragma unroll
  for (int i = 0; i < 16; ++i) oacc[i] = (f32x4){0.f, 0.f, 0.f, 0.f};
  float mrun[4] = {NEGBIG, NEGBIG, NEGBIG, NEGBIG};
  float lrun[4] = {0.f, 0.f, 0.f, 0.f};
  const u16* kbase = Kg + (size_t)b * TT * CC + h2 * DD + (tid & 31) * 8;
  const int krow = tid >> 5;
  const u16* vbase = Vt + (size_t)(bh * DD + (tid >> 2)) * TT + (tid & 3) * 8;
  u16* myP = Ps + wid * 16 * 40;
  for (int kt = 0; kt < TT / 32; ++kt){
    if (mask[b * TT + kt * 32] == 0) break;   // prefix mask -> suffix fully masked
    __syncthreads();
#pragma unroll
    for (int i = 0; i < 4; ++i){
      const int r = i * 8 + krow;
      uint4 tk = *(const uint4*)(kbase + (size_t)(kt * 32 + r) * CC);
      *(uint4*)&Ks[r * 264 + (tid & 31) * 8] = tk;
    }
#pragma unroll
    for (int i = 0; i < 4; ++i){
      uint4 tv = *(const uint4*)(vbase + (size_t)i * 64 * TT + kt * 32);
      *(uint4*)&Vs[(i * 64 + (tid >> 2)) * 40 + (tid & 3) * 8] = tv;
    }
    __syncthreads();
    // S tile 16 q x 32 k  (D layout: row=(lg*4+j)=q, col=la=k within frag)
    f32x4 sfr[2];
#pragma unroll
    for (int fn = 0; fn < 2; ++fn){
      f32x4 s = (f32x4){0.f, 0.f, 0.f, 0.f};
#pragma unroll
      for (int kd = 0; kd < 8; ++kd){
        bf16x8 kf = *(const bf16x8*)&Ks[(fn * 16 + la) * 264 + kd * 32 + lg * 8];
        s = __builtin_amdgcn_mfma_f32_16x16x32_bf16(qf[kd], kf, s, 0, 0, 0);
      }
      sfr[fn] = s;
    }
    const int colb = b * TT + kt * 32 + la;
#pragma unroll
    for (int fn = 0; fn < 2; ++fn){
      const float mk = mask[colb + fn * 16] ? 0.f : NEGBIG;
      sfr[fn] = sfr[fn] * SCALEV + mk;
    }
    float al[4];
#pragma unroll
    for (int j = 0; j < 4; ++j){
      float tm = fmaxf(sfr[0][j], sfr[1][j]);
      tm = fmaxf(tm, __shfl_xor(tm, 1));
      tm = fmaxf(tm, __shfl_xor(tm, 2));
      tm = fmaxf(tm, __shfl_xor(tm, 4));
      tm = fmaxf(tm, __shfl_xor(tm, 8));
      const float mn = fmaxf(mrun[j], tm);
      al[j] = expf(mrun[j] - mn);
      mrun[j] = mn;
    }
    float tsum[4] = {0.f, 0.f, 0.f, 0.f};
#pragma unroll
    for (int fn = 0; fn < 2; ++fn){
#pragma unroll
      for (int j = 0; j < 4; ++j){
        const float p = expf(sfr[fn][j] - mrun[j]);
        tsum[j] += p;
        myP[(lg * 4 + j) * 40 + fn * 16 + la] = f2bf(p);
      }
    }
#pragma unroll
    for (int j = 0; j < 4; ++j){
      tsum[j] += __shfl_xor(tsum[j], 1);
      tsum[j] += __shfl_xor(tsum[j], 2);
      tsum[j] += __shfl_xor(tsum[j], 4);
      tsum[j] += __shfl_xor(tsum[j], 8);
      lrun[j] = lrun[j] * al[j] + tsum[j];
    }
    // redistribute alpha from row-layout (groups of 16 lanes) to col-layout (q = la)
    const int src = (la >> 2) * 16;
    const float a0 = __shfl(al[0], src), a1 = __shfl(al[1], src);
    const float a2 = __shfl(al[2], src), a3 = __shfl(al[3], src);
    const int jq = la & 3;
    const float aq = (jq == 0) ? a0 : (jq == 1) ? a1 : (jq == 2) ? a2 : a3;
#pragma unroll
    for (int i = 0; i < 16; ++i) oacc[i] *= aq;
    // PV: Ot[d][q] += sum_k Vt[d][k] * P[q][k]
    bf16x8 pf = *(const bf16x8*)&myP[la * 40 + lg * 8];
#pragma unroll
    for (int mi = 0; mi < 16; ++mi){
      bf16x8 vf = *(const bf16x8*)&Vs[(mi * 16 + la) * 40 + lg * 8];
      oacc[mi] = __builtin_amdgcn_mfma_f32_16x16x32_bf16(vf, pf, oacc[mi], 0, 0, 0);
    }
  }
  const int src = (la >> 2) * 16;
  const float l0 = __shfl(lrun[0], src), l1 = __shfl(lrun[1], src);
  const float l2 = __shfl(lrun[2], src), l3 = __shfl(lrun[3], src);
  const int jq = la & 3;
  const float lq = (jq == 0) ? l0 : (jq == 1) ? l1 : (jq == 2) ? l2 : l3;
  const float inv = 1.f / lq;
  u16* orow = Oa + (size_t)(b * TT + qt * 64 + wid * 16 + la) * CC + h2 * DD + lg * 4;
#pragma unroll
  for (int mi = 0; mi < 16; ++mi){
    ushort4 p;
    p.x = f2bf(oacc[mi][0] * inv); p.y = f2bf(oacc[mi][1] * inv);
    p.z = f2bf(oacc[mi][2] * inv); p.w = f2bf(oacc[mi][3] * inv);
    *(ushort4*)(orow + mi * 16) = p;
  }
}

// ---------------- dwconv(tc) + bias + exact GELU ----------------
__global__ __launch_bounds__(256) void tc_gelu(const u16* __restrict__ y2,
    const float* __restrict__ w, const float* __restrict__ bias, u16* __restrict__ y3){
  const int row = blockIdx.x, tid = threadIdx.x;
  const int t = row & (TT - 1);
  const int c = tid * 4;
  ushort4 z4; z4.x = z4.y = z4.z = z4.w = 0;
  const ushort4 u0 = *(const ushort4*)(y2 + (size_t)row * CC + c);
  const ushort4 um = (t > 0)      ? *(const ushort4*)(y2 + (size_t)(row - 1) * CC + c) : z4;
  const ushort4 up = (t < TT - 1) ? *(const ushort4*)(y2 + (size_t)(row + 1) * CC + c) : z4;
  const float am[4] = {bf2f(um.x), bf2f(um.y), bf2f(um.z), bf2f(um.w)};
  const float a0[4] = {bf2f(u0.x), bf2f(u0.y), bf2f(u0.z), bf2f(u0.w)};
  const float ap[4] = {bf2f(up.x), bf2f(up.y), bf2f(up.z), bf2f(up.w)};
  u16 pv[4];
#pragma unroll
  for (int i = 0; i < 4; ++i){
    const float* wp = w + (c + i) * 3;
    const float yv = am[i] * wp[0] + a0[i] * wp[1] + ap[i] * wp[2] + bias[c + i];
    const float ge = 0.5f * yv * (1.f + erff(yv * 0.7071067811865475f));
    pv[i] = f2bf(ge);
  }
  ushort4 p; p.x = pv[0]; p.y = pv[1]; p.z = pv[2]; p.w = pv[3];
  *(ushort4*)(y3 + (size_t)row * CC + c) = p;
}

extern "C" void kernel_launch(void* const* d_in, const int* in_sizes, int n_in,
                              void* d_out, int out_size, void* d_ws, size_t ws_size,
                              hipStream_t stream){
  const float* x     = (const float*)d_in[0];
  const int*   mask  = (const int*)d_in[1];
  const float* n1g   = (const float*)d_in[2];
  const float* n1b   = (const float*)d_in[3];
  const float* qconv = (const float*)d_in[4];
  const float* kconv = (const float*)d_in[5];
  const float* vconv = (const float*)d_in[6];
  const float* qg    = (const float*)d_in[7];
  const float* qbe   = (const float*)d_in[8];
  const float* kg    = (const float*)d_in[9];
  const float* kbe   = (const float*)d_in[10];
  const float* vg    = (const float*)d_in[11];
  const float* vbe   = (const float*)d_in[12];
  const float* q1w   = (const float*)d_in[13];
  const float* q1b   = (const float*)d_in[14];
  const float* k1w   = (const float*)d_in[15];
  const float* k1b   = (const float*)d_in[16];
  const float* v1w   = (const float*)d_in[17];
  const float* v1b   = (const float*)d_in[18];
  const float* pw    = (const float*)d_in[19];
  const float* pb    = (const float*)d_in[20];
  const float* n2g   = (const float*)d_in[21];
  const float* n2b   = (const float*)d_in[22];
  const float* l1w   = (const float*)d_in[23];
  const float* l1b   = (const float*)d_in[24];
  const float* tcw   = (const float*)d_in[25];
  const float* tcb   = (const float*)d_in[26];
  const float* l2w   = (const float*)d_in[27];
  const float* l2b   = (const float*)d_in[28];
  (void)in_sizes; (void)n_in; (void)out_size; (void)ws_size;

  char* ws = (char*)d_ws;
  const size_t MB = (size_t)1 << 20;
  u16* wq  = (u16*)(ws + 0 * MB);
  u16* wk  = (u16*)(ws + 2 * MB);
  u16* wv  = (u16*)(ws + 4 * MB);
  u16* wp2 = (u16*)(ws + 6 * MB);
  u16* wl1 = (u16*)(ws + 8 * MB);
  u16* wl2 = (u16*)(ws + 10 * MB);
  float* hbuf = (float*)(ws + 12 * MB);   // 32 MB; reused as x2 after attention
  float* x2   = hbuf;
  u16* qn  = (u16*)(ws + 44 * MB);
  u16* kn  = (u16*)(ws + 60 * MB);
  u16* vn  = (u16*)(ws + 76 * MB);
  u16* Qb  = (u16*)(ws + 92 * MB);
  u16* Kb  = (u16*)(ws + 108 * MB);
  u16* Vtb = (u16*)(ws + 124 * MB);
  u16* AO  = qn;    // attnout  (qn dead after q1 GEMM)
  u16* y1  = kn;    // LN2 out  (kn dead after k1 GEMM)
  u16* y2  = vn;    // lin1 out (vn dead after v1 GEMM)
  u16* y3  = Qb;    // gelu out (Q dead after flash)

  conv_w_kernel<<<1024, 256, 0, stream>>>(q1w, k1w, v1w, pw, l1w, l2w, wq, wk, wv, wp2, wl1, wl2);
  ln_rows<0><<<MM, 256, 0, stream>>>(x, n1g, n1b, hbuf);
  qkv_pre<<<MM, 256, 0, stream>>>(hbuf, mask, qconv, kconv, vconv,
                                  qg, qbe, kg, kbe, vg, vbe, qn, kn, vn);
  gemm_bt<0><<<dim3(64, 8), 256, 0, stream>>>(qn, wq, q1b, Qb, nullptr, nullptr);
  gemm_bt<0><<<dim3(64, 8), 256, 0, stream>>>(kn, wk, k1b, Kb, nullptr, nullptr);
  gemm_bt<3><<<dim3(64, 8), 256, 0, stream>>>(vn, wv, v1b, Vtb, nullptr, nullptr);
  flash_attn<<<dim3(32, 16), 256, 0, stream>>>(Qb, Kb, Vtb, mask, AO);
  gemm_bt<1><<<dim3(64, 8), 256, 0, stream>>>(AO, wp2, pb, x2, x, mask);
  ln_rows<1><<<MM, 256, 0, stream>>>(x2, n2g, n2b, y1);
  gemm_bt<0><<<dim3(64, 8), 256, 0, stream>>>(y1, wl1, l1b, y2, nullptr, nullptr);
  tc_gelu<<<MM, 256, 0, stream>>>(y2, tcw, tcb, y3);
  gemm_bt<2><<<dim3(64, 8), 256, 0, stream>>>(y3, wl2, l2b, (float*)d_out, x2, nullptr);
}

// Round 3
// 453.991 us; speedup vs baseline: 1.3312x; 1.3312x over previous
//
#include <hip/hip_runtime.h>

#define BB 4
#define TT 2048
#define CC 1024
#define HH 4
#define DD 256
#define MM (BB*TT)

#define EPSV 1e-5f
#define NEGBIG (-1e30f)
#define SCALEV 0.0625f   // 1/sqrt(256)

typedef unsigned short u16;
typedef unsigned int   u32;
typedef __bf16 bf16x8 __attribute__((ext_vector_type(8)));
typedef float  f32x4  __attribute__((ext_vector_type(4)));

typedef u32 __attribute__((address_space(1))) gu32;
typedef u32 __attribute__((address_space(3))) lu32;

__device__ __forceinline__ u16 f2bf(float f){
  u32 u = __builtin_bit_cast(u32, f);
  u32 r = (u + 0x7fffu + ((u >> 16) & 1u)) >> 16;
  return (u16)r;
}
__device__ __forceinline__ float bf2f(u16 h){
  u32 u = ((u32)h) << 16;
  return __builtin_bit_cast(float, u);
}
__device__ __forceinline__ void gload_lds16(const u16* g, u16* l){
  __builtin_amdgcn_global_load_lds((const gu32*)g, (lu32*)l, 16, 0, 0);
}

// ---------------- weight f32 -> bf16 ----------------
__global__ __launch_bounds__(256) void conv_w_kernel(
    const float* __restrict__ w0, const float* __restrict__ w1, const float* __restrict__ w2,
    const float* __restrict__ w3, const float* __restrict__ w4, const float* __restrict__ w5,
    u16* __restrict__ o0, u16* __restrict__ o1, u16* __restrict__ o2,
    u16* __restrict__ o3, u16* __restrict__ o4, u16* __restrict__ o5){
  const int i = (blockIdx.x * 256 + threadIdx.x) * 4;
  const float* wsrc[6] = {w0,w1,w2,w3,w4,w5};
  u16* odst[6] = {o0,o1,o2,o3,o4,o5};
#pragma unroll
  for (int k = 0; k < 6; ++k){
    float4 v = *(const float4*)(wsrc[k] + i);
    ushort4 p; p.x=f2bf(v.x); p.y=f2bf(v.y); p.z=f2bf(v.z); p.w=f2bf(v.w);
    *(ushort4*)(odst[k] + i) = p;
  }
}

// ---------------- channel LayerNorm over C per (b,t) row ----------------
template<int OUTBF>
__global__ __launch_bounds__(256) void ln_rows(const float* __restrict__ x,
    const float* __restrict__ g, const float* __restrict__ be, void* __restrict__ out){
  const int row = blockIdx.x, tid = threadIdx.x;
  const float4 v = ((const float4*)(x + (size_t)row * CC))[tid];
  float s  = v.x + v.y + v.z + v.w;
  float ss = v.x*v.x + v.y*v.y + v.z*v.z + v.w*v.w;
  __shared__ float sb[8];
#pragma unroll
  for (int o = 1; o < 64; o <<= 1){ s += __shfl_xor(s, o); ss += __shfl_xor(ss, o); }
  const int wid = tid >> 6, lane = tid & 63;
  if (lane == 0){ sb[wid] = s; sb[4 + wid] = ss; }
  __syncthreads();
  s  = sb[0] + sb[1] + sb[2] + sb[3];
  ss = sb[4] + sb[5] + sb[6] + sb[7];
  const float mu = s * (1.0f / CC);
  const float rstd = rsqrtf(ss * (1.0f / CC) - mu * mu + EPSV);
  const float4 gg = ((const float4*)g)[tid];
  const float4 bb = ((const float4*)be)[tid];
  const float r0 = (v.x - mu) * rstd * gg.x + bb.x;
  const float r1 = (v.y - mu) * rstd * gg.y + bb.y;
  const float r2 = (v.z - mu) * rstd * gg.z + bb.z;
  const float r3 = (v.w - mu) * rstd * gg.w + bb.w;
  if (OUTBF){
    ushort4 p; p.x=f2bf(r0); p.y=f2bf(r1); p.z=f2bf(r2); p.w=f2bf(r3);
    *(ushort4*)((u16*)out + (size_t)row * CC + tid * 4) = p;
  } else {
    ((float4*)((float*)out + (size_t)row * CC))[tid] = make_float4(r0, r1, r2, r3);
  }
}

// ------------ fused q/k/v: dwconv3 (pad1) * mask -> LN -> bf16 ------------
__global__ __launch_bounds__(256) void qkv_pre(const float* __restrict__ h,
    const int* __restrict__ mask,
    const float* __restrict__ qw, const float* __restrict__ kw, const float* __restrict__ vw,
    const float* __restrict__ qg, const float* __restrict__ qb2,
    const float* __restrict__ kg, const float* __restrict__ kb2,
    const float* __restrict__ vg, const float* __restrict__ vb2,
    u16* __restrict__ qn, u16* __restrict__ kn, u16* __restrict__ vn){
  const int row = blockIdx.x, tid = threadIdx.x;
  const int t = row & (TT - 1);
  const float mf = mask[row] ? 1.f : 0.f;
  const float4 z4 = make_float4(0.f, 0.f, 0.f, 0.f);
  const float4 x0 = ((const float4*)(h + (size_t)row * CC))[tid];
  const float4 xm = (t > 0)      ? ((const float4*)(h + (size_t)(row - 1) * CC))[tid] : z4;
  const float4 xp = (t < TT - 1) ? ((const float4*)(h + (size_t)(row + 1) * CC))[tid] : z4;
  const int c = tid * 4;
  const float am[4] = {xm.x, xm.y, xm.z, xm.w};
  const float a0[4] = {x0.x, x0.y, x0.z, x0.w};
  const float ap[4] = {xp.x, xp.y, xp.z, xp.w};
  float yq[4], yk[4], yv[4];
  float sq=0.f, ssq=0.f, sk=0.f, ssk=0.f, sv=0.f, ssv=0.f;
#pragma unroll
  for (int i = 0; i < 4; ++i){
    const float* qwp = qw + (c + i) * 3;
    const float* kwp = kw + (c + i) * 3;
    const float* vwp = vw + (c + i) * 3;
    const float q_ = (am[i]*qwp[0] + a0[i]*qwp[1] + ap[i]*qwp[2]) * mf;
    const float k_ = (am[i]*kwp[0] + a0[i]*kwp[1] + ap[i]*kwp[2]) * mf;
    const float v_ = (am[i]*vwp[0] + a0[i]*vwp[1] + ap[i]*vwp[2]) * mf;
    yq[i]=q_; yk[i]=k_; yv[i]=v_;
    sq+=q_; ssq+=q_*q_; sk+=k_; ssk+=k_*k_; sv+=v_; ssv+=v_*v_;
  }
  __shared__ float sb[24];
#pragma unroll
  for (int o = 1; o < 64; o <<= 1){
    sq += __shfl_xor(sq, o); ssq += __shfl_xor(ssq, o);
    sk += __shfl_xor(sk, o); ssk += __shfl_xor(ssk, o);
    sv += __shfl_xor(sv, o); ssv += __shfl_xor(ssv, o);
  }
  const int wid = tid >> 6, lane = tid & 63;
  if (lane == 0){
    sb[wid]=sq; sb[4+wid]=ssq; sb[8+wid]=sk; sb[12+wid]=ssk; sb[16+wid]=sv; sb[20+wid]=ssv;
  }
  __syncthreads();
  sq  = sb[0]+sb[1]+sb[2]+sb[3];    ssq = sb[4]+sb[5]+sb[6]+sb[7];
  sk  = sb[8]+sb[9]+sb[10]+sb[11];  ssk = sb[12]+sb[13]+sb[14]+sb[15];
  sv  = sb[16]+sb[17]+sb[18]+sb[19];ssv = sb[20]+sb[21]+sb[22]+sb[23];
  {
    const float mu = sq * (1.f/CC), rstd = rsqrtf(ssq*(1.f/CC) - mu*mu + EPSV);
    ushort4 p;
    p.x = f2bf((yq[0]-mu)*rstd*qg[c+0] + qb2[c+0]);
    p.y = f2bf((yq[1]-mu)*rstd*qg[c+1] + qb2[c+1]);
    p.z = f2bf((yq[2]-mu)*rstd*qg[c+2] + qb2[c+2]);
    p.w = f2bf((yq[3]-mu)*rstd*qg[c+3] + qb2[c+3]);
    *(ushort4*)(qn + (size_t)row * CC + c) = p;
  }
  {
    const float mu = sk * (1.f/CC), rstd = rsqrtf(ssk*(1.f/CC) - mu*mu + EPSV);
    ushort4 p;
    p.x = f2bf((yk[0]-mu)*rstd*kg[c+0] + kb2[c+0]);
    p.y = f2bf((yk[1]-mu)*rstd*kg[c+1] + kb2[c+1]);
    p.z = f2bf((yk[2]-mu)*rstd*kg[c+2] + kb2[c+2]);
    p.w = f2bf((yk[3]-mu)*rstd*kg[c+3] + kb2[c+3]);
    *(ushort4*)(kn + (size_t)row * CC + c) = p;
  }
  {
    const float mu = sv * (1.f/CC), rstd = rsqrtf(ssv*(1.f/CC) - mu*mu + EPSV);
    ushort4 p;
    p.x = f2bf((yv[0]-mu)*rstd*vg[c+0] + vb2[c+0]);
    p.y = f2bf((yv[1]-mu)*rstd*vg[c+1] + vb2[c+1]);
    p.z = f2bf((yv[2]-mu)*rstd*vg[c+2] + vb2[c+2]);
    p.w = f2bf((yv[3]-mu)*rstd*vg[c+3] + vb2[c+3]);
    *(ushort4*)(vn + (size_t)row * CC + c) = p;
  }
}

// ---------------- bf16 "bt" GEMM: C[m,n] = sum_k A[m,k]*W[n,k] + bias[n] ----------------
template<int MODE>
__global__ __launch_bounds__(256) void gemm_bt(
    const u16* __restrict__ A, const u16* __restrict__ Bw,
    const float* __restrict__ bias, void* __restrict__ out,
    const float* __restrict__ resid, const int* __restrict__ mask){
  __shared__ u16 As[128 * 32];
  __shared__ u16 Bs[128 * 32];
  const int tid = threadIdx.x, lane = tid & 63, wid = tid >> 6;
  const int wr = wid >> 1, wc = wid & 1;
  const int bm = blockIdx.x, bn = blockIdx.y;
  f32x4 acc[4][4];
#pragma unroll
  for (int i = 0; i < 4; ++i)
#pragma unroll
    for (int j = 0; j < 4; ++j) acc[i][j] = (f32x4){0.f, 0.f, 0.f, 0.f};
  const u16* gA = A  + (size_t)(bm * 128 + wid * 32 + (lane >> 2)) * CC + (lane & 3) * 8;
  const u16* gB = Bw + (size_t)(bn * 128 + wid * 32 + (lane >> 2)) * CC + (lane & 3) * 8;
  u16* lA = &As[wid * 1024];
  u16* lB = &Bs[wid * 1024];
  const int la = lane & 15, lg8 = (lane >> 4) * 8;
  for (int kt = 0; kt < CC / 32; ++kt){
    gload_lds16(gA + kt * 32, lA);
    gload_lds16(gA + kt * 32 + (size_t)16 * CC, lA + 512);
    gload_lds16(gB + kt * 32, lB);
    gload_lds16(gB + kt * 32 + (size_t)16 * CC, lB + 512);
    __syncthreads();
    bf16x8 af[4], bf[4];
#pragma unroll
    for (int mi = 0; mi < 4; ++mi) af[mi] = *(const bf16x8*)&As[(wr*64 + mi*16 + la)*32 + lg8];
#pragma unroll
    for (int ni = 0; ni < 4; ++ni) bf[ni] = *(const bf16x8*)&Bs[(wc*64 + ni*16 + la)*32 + lg8];
#pragma unroll
    for (int mi = 0; mi < 4; ++mi)
#pragma unroll
      for (int ni = 0; ni < 4; ++ni)
        acc[mi][ni] = __builtin_amdgcn_mfma_f32_16x16x32_bf16(af[mi], bf[ni], acc[mi][ni], 0, 0, 0);
    __syncthreads();
  }
  const int lg = lane >> 4;
#pragma unroll
  for (int mi = 0; mi < 4; ++mi){
    const int mb = bm * 128 + wr * 64 + mi * 16 + lg * 4;
#pragma unroll
    for (int ni = 0; ni < 4; ++ni){
      const int n = bn * 128 + wc * 64 + ni * 16 + la;
      const float bz = bias[n];
      if (MODE == 0){
        u16* o = (u16*)out;
#pragma unroll
        for (int j = 0; j < 4; ++j) o[(size_t)(mb + j) * CC + n] = f2bf(acc[mi][ni][j] + bz);
      } else if (MODE == 1){
        float* o = (float*)out;
#pragma unroll
        for (int j = 0; j < 4; ++j){
          const int m = mb + j;
          const float mf = mask[m] ? 1.f : 0.f;
          o[(size_t)m * CC + n] = (acc[mi][ni][j] + bz) * mf + resid[(size_t)m * CC + n];
        }
      } else if (MODE == 2){
        float* o = (float*)out;
#pragma unroll
        for (int j = 0; j < 4; ++j){
          const int m = mb + j;
          o[(size_t)m * CC + n] = acc[mi][ni][j] + bz + resid[(size_t)m * CC + n];
        }
      } else {
        u16* o = (u16*)out;
        const int bq = mb >> 11, tq = mb & (TT - 1);
        const int hq = n >> 8, dq = n & 255;
        ushort4 p;
        p.x = f2bf(acc[mi][ni][0] + bz); p.y = f2bf(acc[mi][ni][1] + bz);
        p.z = f2bf(acc[mi][ni][2] + bz); p.w = f2bf(acc[mi][ni][3] + bz);
        *(ushort4*)&o[(size_t)((bq * HH + hq) * DD + dq) * TT + tq] = p;
      }
    }
  }
}

// ---------------- flash attention v2: KVB=64, swizzled LDS, async staging ----------------
// Q,K in (B*T, C) bf16; V pre-transposed to (B,H,D,T) bf16.
// exp2-domain online softmax; prefix length computed once via ballot.
__global__ __launch_bounds__(256) void flash_attn(
    const u16* __restrict__ Q, const u16* __restrict__ Kg,
    const u16* __restrict__ Vt, const int* __restrict__ mask,
    u16* __restrict__ Oa){
  __shared__ __align__(16) u16 Ks[64 * 256];   // row k (stride 512B), XOR-swz ((r&7)<<4)
  __shared__ __align__(16) u16 Vs[256 * 64];   // row d (stride 128B), XOR-swz ((d&7)<<4)
  __shared__ __align__(16) u16 Ps[4][16 * 64]; // per-wave, row q (stride 128B), XOR-swz ((q&7)<<4)
  const int qt = blockIdx.x, bh = blockIdx.y;
  const int b = bh >> 2, h2 = bh & 3;
  const int tid = threadIdx.x, lane = tid & 63, wid = tid >> 6;
  const int la = lane & 15, lg = lane >> 4;

  // ---- sequence length via two ballot rounds (prefix mask, len in [1024,2048]) ----
  const int* mrow = mask + b * TT;
  int len = 1024;
  {
    unsigned long long bal = __ballot(mrow[1024 + lane * 16] != 0);
    int ones = __popcll(bal);
    if (ones > 0){
      int lo = 1024 + (ones - 1) * 16;
      unsigned long long bal2 = __ballot(mrow[lo + la] != 0);
      len = lo + __popcll(bal2 & 0xFFFFull);
    }
  }
  const int nkt = (len + 63) >> 6;

  bf16x8 qf[8];
  const u16* qrow = Q + (size_t)(b * TT + qt * 64 + wid * 16 + la) * CC + h2 * DD + lg * 8;
#pragma unroll
  for (int kd = 0; kd < 8; ++kd) qf[kd] = *(const bf16x8*)(qrow + kd * 32);

  f32x4 oacc[16];
#pragma unroll
  for (int i = 0; i < 16; ++i) oacc[i] = (f32x4){0.f, 0.f, 0.f, 0.f};
  float mrun[4] = {NEGBIG, NEGBIG, NEGBIG, NEGBIG};
  float lrun[4] = {0.f, 0.f, 0.f, 0.f};

  const char* KsB = (const char*)Ks;
  const char* VsB = (const char*)Vs;
  char* PsB = (char*)&Ps[wid][0];

  // ---- prologue: stage K(0), V(0) (pre-swizzled global source, linear LDS dest) ----
#pragma unroll
  for (int i = 0; i < 8; ++i){
    const int r = (i * 4 + wid) * 2 + (lane >> 5);
    const int yy = ((lane & 31) * 16) ^ ((r & 7) << 4);
    gload_lds16(Kg + (size_t)(b * TT + r) * CC + h2 * DD + (yy >> 1), &Ks[(i * 4 + wid) * 512]);
  }
#pragma unroll
  for (int i = 0; i < 8; ++i){
    const int d = (i * 4 + wid) * 8 + (lane >> 3);
    const int yy = ((lane & 7) * 16) ^ ((d & 7) << 4);
    gload_lds16(Vt + (size_t)(bh * DD + d) * TT + (yy >> 1), &Vs[(i * 4 + wid) * 512]);
  }
  __syncthreads();

  const float sc2 = SCALEV * 1.44269504f;   // fold log2(e): softmax in exp2 domain
  for (int kt = 0; kt < nkt; ++kt){
    // ---- phase A: QK^T + softmax (V(kt) loads drained by prologue/prev b-barrier chain) ----
    f32x4 sfr[4];
#pragma unroll
    for (int fn = 0; fn < 4; ++fn){
      f32x4 s = (f32x4){0.f, 0.f, 0.f, 0.f};
      const int rk = fn * 16 + la;
      const int swz = (rk & 7) << 4;
#pragma unroll
      for (int kd = 0; kd < 8; ++kd){
        bf16x8 kf = *(const bf16x8*)(KsB + rk * 512 + ((kd * 64 + lg * 16) ^ swz));
        s = __builtin_amdgcn_mfma_f32_16x16x32_bf16(qf[kd], kf, s, 0, 0, 0);
      }
      sfr[fn] = s;
    }
    const int k0 = kt * 64;
#pragma unroll
    for (int fn = 0; fn < 4; ++fn){
      const float mk = (k0 + fn * 16 + la < len) ? 0.f : NEGBIG;
      sfr[fn] = sfr[fn] * sc2 + mk;
    }
    float al[4];
#pragma unroll
    for (int j = 0; j < 4; ++j){
      float tm = fmaxf(fmaxf(sfr[0][j], sfr[1][j]), fmaxf(sfr[2][j], sfr[3][j]));
      tm = fmaxf(tm, __shfl_xor(tm, 1));
      tm = fmaxf(tm, __shfl_xor(tm, 2));
      tm = fmaxf(tm, __shfl_xor(tm, 4));
      tm = fmaxf(tm, __shfl_xor(tm, 8));
      const float mn = fmaxf(mrun[j], tm);
      al[j] = __builtin_exp2f(mrun[j] - mn);
      mrun[j] = mn;
    }
    float tsum[4] = {0.f, 0.f, 0.f, 0.f};
#pragma unroll
    for (int j = 0; j < 4; ++j){
      const int q = lg * 4 + j;
      const int swq = (q & 7) << 4;
      char* prow = PsB + q * 128;
#pragma unroll
      for (int fn = 0; fn < 4; ++fn){
        const float p = __builtin_exp2f(sfr[fn][j] - mrun[j]);
        tsum[j] += p;
        *(u16*)(prow + (((fn * 16 + la) * 2) ^ swq)) = f2bf(p);
      }
    }
#pragma unroll
    for (int j = 0; j < 4; ++j){
      tsum[j] += __shfl_xor(tsum[j], 1);
      tsum[j] += __shfl_xor(tsum[j], 2);
      tsum[j] += __shfl_xor(tsum[j], 4);
      tsum[j] += __shfl_xor(tsum[j], 8);
      lrun[j] = lrun[j] * al[j] + tsum[j];
    }
    __syncthreads();   // b1: Ks readers done; V(kt) drained; Ps visible to own wave
    // ---- phase B: issue K(kt+1) first (hides under PV), then PV ----
    if (kt + 1 < nkt){
#pragma unroll
      for (int i = 0; i < 8; ++i){
        const int r = (i * 4 + wid) * 2 + (lane >> 5);
        const int yy = ((lane & 31) * 16) ^ ((r & 7) << 4);
        gload_lds16(Kg + (size_t)(b * TT + (kt + 1) * 64 + r) * CC + h2 * DD + (yy >> 1),
                    &Ks[(i * 4 + wid) * 512]);
      }
    }
    {
      const int src = (la >> 2) * 16;
      const float a0 = __shfl(al[0], src), a1 = __shfl(al[1], src);
      const float a2 = __shfl(al[2], src), a3 = __shfl(al[3], src);
      const int jq = la & 3;
      const float aq = (jq == 0) ? a0 : (jq == 1) ? a1 : (jq == 2) ? a2 : a3;
#pragma unroll
      for (int i = 0; i < 16; ++i) oacc[i] *= aq;
    }
    bf16x8 pf0, pf1;
    {
      const int swp = (la & 7) << 4;
      pf0 = *(const bf16x8*)(PsB + la * 128 + ((lg * 16) ^ swp));
      pf1 = *(const bf16x8*)(PsB + la * 128 + ((64 + lg * 16) ^ swp));
    }
#pragma unroll
    for (int mi = 0; mi < 16; ++mi){
      const int d = mi * 16 + la;
      const int swv = (d & 7) << 4;
      bf16x8 vf0 = *(const bf16x8*)(VsB + d * 128 + ((lg * 16) ^ swv));
      bf16x8 vf1 = *(const bf16x8*)(VsB + d * 128 + ((64 + lg * 16) ^ swv));
      oacc[mi] = __builtin_amdgcn_mfma_f32_16x16x32_bf16(vf0, pf0, oacc[mi], 0, 0, 0);
      oacc[mi] = __builtin_amdgcn_mfma_f32_16x16x32_bf16(vf1, pf1, oacc[mi], 0, 0, 0);
    }
    __syncthreads();   // b2: Vs readers done; K(kt+1) drained
    if (kt + 1 < nkt){
#pragma unroll
      for (int i = 0; i < 8; ++i){
        const int d = (i * 4 + wid) * 8 + (lane >> 3);
        const int yy = ((lane & 7) * 16) ^ ((d & 7) << 4);
        gload_lds16(Vt + (size_t)(bh * DD + d) * TT + (kt + 1) * 64 + (yy >> 1),
                    &Vs[(i * 4 + wid) * 512]);
      }
    }
  }
  // ---- epilogue ----
  const int src = (la >> 2) * 16;
  const float l0 = __shfl(lrun[0], src), l1 = __shfl(lrun[1], src);
  const float l2 = __shfl(lrun[2], src), l3 = __shfl(lrun[3], src);
  const int jq = la & 3;
  const float lq = (jq == 0) ? l0 : (jq == 1) ? l1 : (jq == 2) ? l2 : l3;
  const float inv = 1.f / lq;
  u16* orow = Oa + (size_t)(b * TT + qt * 64 + wid * 16 + la) * CC + h2 * DD + lg * 4;
#pragma unroll
  for (int mi = 0; mi < 16; ++mi){
    ushort4 p;
    p.x = f2bf(oacc[mi][0] * inv); p.y = f2bf(oacc[mi][1] * inv);
    p.z = f2bf(oacc[mi][2] * inv); p.w = f2bf(oacc[mi][3] * inv);
    *(ushort4*)(orow + mi * 16) = p;
  }
}

// ---------------- dwconv(tc) + bias + exact GELU ----------------
__global__ __launch_bounds__(256) void tc_gelu(const u16* __restrict__ y2,
    const float* __restrict__ w, const float* __restrict__ bias, u16* __restrict__ y3){
  const int row = blockIdx.x, tid = threadIdx.x;
  const int t = row & (TT - 1);
  const int c = tid * 4;
  ushort4 z4; z4.x = z4.y = z4.z = z4.w = 0;
  const ushort4 u0 = *(const ushort4*)(y2 + (size_t)row * CC + c);
  const ushort4 um = (t > 0)      ? *(const ushort4*)(y2 + (size_t)(row - 1) * CC + c) : z4;
  const ushort4 up = (t < TT - 1) ? *(const ushort4*)(y2 + (size_t)(row + 1) * CC + c) : z4;
  const float am[4] = {bf2f(um.x), bf2f(um.y), bf2f(um.z), bf2f(um.w)};
  const float a0[4] = {bf2f(u0.x), bf2f(u0.y), bf2f(u0.z), bf2f(u0.w)};
  const float ap[4] = {bf2f(up.x), bf2f(up.y), bf2f(up.z), bf2f(up.w)};
  u16 pv[4];
#pragma unroll
  for (int i = 0; i < 4; ++i){
    const float* wp = w + (c + i) * 3;
    const float yv = am[i] * wp[0] + a0[i] * wp[1] + ap[i] * wp[2] + bias[c + i];
    const float ge = 0.5f * yv * (1.f + erff(yv * 0.7071067811865475f));
    pv[i] = f2bf(ge);
  }
  ushort4 p; p.x = pv[0]; p.y = pv[1]; p.z = pv[2]; p.w = pv[3];
  *(ushort4*)(y3 + (size_t)row * CC + c) = p;
}

extern "C" void kernel_launch(void* const* d_in, const int* in_sizes, int n_in,
                              void* d_out, int out_size, void* d_ws, size_t ws_size,
                              hipStream_t stream){
  const float* x     = (const float*)d_in[0];
  const int*   mask  = (const int*)d_in[1];
  const float* n1g   = (const float*)d_in[2];
  const float* n1b   = (const float*)d_in[3];
  const float* qconv = (const float*)d_in[4];
  const float* kconv = (const float*)d_in[5];
  const float* vconv = (const float*)d_in[6];
  const float* qg    = (const float*)d_in[7];
  const float* qbe   = (const float*)d_in[8];
  const float* kg    = (const float*)d_in[9];
  const float* kbe   = (const float*)d_in[10];
  const float* vg    = (const float*)d_in[11];
  const float* vbe   = (const float*)d_in[12];
  const float* q1w   = (const float*)d_in[13];
  const float* q1b   = (const float*)d_in[14];
  const float* k1w   = (const float*)d_in[15];
  const float* k1b   = (const float*)d_in[16];
  const float* v1w   = (const float*)d_in[17];
  const float* v1b   = (const float*)d_in[18];
  const float* pw    = (const float*)d_in[19];
  const float* pb    = (const float*)d_in[20];
  const float* n2g   = (const float*)d_in[21];
  const float* n2b   = (const float*)d_in[22];
  const float* l1w   = (const float*)d_in[23];
  const float* l1b   = (const float*)d_in[24];
  const float* tcw   = (const float*)d_in[25];
  const float* tcb   = (const float*)d_in[26];
  const float* l2w   = (const float*)d_in[27];
  const float* l2b   = (const float*)d_in[28];
  (void)in_sizes; (void)n_in; (void)out_size; (void)ws_size;

  char* ws = (char*)d_ws;
  const size_t MB = (size_t)1 << 20;
  u16* wq  = (u16*)(ws + 0 * MB);
  u16* wk  = (u16*)(ws + 2 * MB);
  u16* wv  = (u16*)(ws + 4 * MB);
  u16* wp2 = (u16*)(ws + 6 * MB);
  u16* wl1 = (u16*)(ws + 8 * MB);
  u16* wl2 = (u16*)(ws + 10 * MB);
  float* hbuf = (float*)(ws + 12 * MB);   // 32 MB; reused as x2 after attention
  float* x2   = hbuf;
  u16* qn  = (u16*)(ws + 44 * MB);
  u16* kn  = (u16*)(ws + 60 * MB);
  u16* vn  = (u16*)(ws + 76 * MB);
  u16* Qb  = (u16*)(ws + 92 * MB);
  u16* Kb  = (u16*)(ws + 108 * MB);
  u16* Vtb = (u16*)(ws + 124 * MB);
  u16* AO  = qn;    // attnout  (qn dead after q1 GEMM)
  u16* y1  = kn;    // LN2 out  (kn dead after k1 GEMM)
  u16* y2  = vn;    // lin1 out (vn dead after v1 GEMM)
  u16* y3  = Qb;    // gelu out (Q dead after flash)

  conv_w_kernel<<<1024, 256, 0, stream>>>(q1w, k1w, v1w, pw, l1w, l2w, wq, wk, wv, wp2, wl1, wl2);
  ln_rows<0><<<MM, 256, 0, stream>>>(x, n1g, n1b, hbuf);
  qkv_pre<<<MM, 256, 0, stream>>>(hbuf, mask, qconv, kconv, vconv,
                                  qg, qbe, kg, kbe, vg, vbe, qn, kn, vn);
  gemm_bt<0><<<dim3(64, 8), 256, 0, stream>>>(qn, wq, q1b, Qb, nullptr, nullptr);
  gemm_bt<0><<<dim3(64, 8), 256, 0, stream>>>(kn, wk, k1b, Kb, nullptr, nullptr);
  gemm_bt<3><<<dim3(64, 8), 256, 0, stream>>>(vn, wv, v1b, Vtb, nullptr, nullptr);
  flash_attn<<<dim3(32, 16), 256, 0, stream>>>(Qb, Kb, Vtb, mask, AO);
  gemm_bt<1><<<dim3(64, 8), 256, 0, stream>>>(AO, wp2, pb, x2, x, mask);
  ln_rows<1><<<MM, 256, 0, stream>>>(x2, n2g, n2b, y1);
  gemm_bt<0><<<dim3(64, 8), 256, 0, stream>>>(y1, wl1, l1b, y2, nullptr, nullptr);
  tc_gelu<<<MM, 256, 0, stream>>>(y2, tcw, tcb, y3);
  gemm_bt<2><<<dim3(64, 8), 256, 0, stream>>>(y3, wl2, l2b, (float*)d_out, x2, nullptr);
}

// Round 4
// 377.500 us; speedup vs baseline: 1.6010x; 1.2026x over previous
//
#include <hip/hip_runtime.h>

#define BB 4
#define TT 2048
#define CC 1024
#define HH 4
#define DD 256
#define MM (BB*TT)

#define EPSV 1e-5f
#define NEGBIG (-1e30f)
#define SCALEV 0.0625f   // 1/sqrt(256)

typedef unsigned short u16;
typedef unsigned int   u32;
typedef __bf16 bf16x8 __attribute__((ext_vector_type(8)));
typedef float  f32x4  __attribute__((ext_vector_type(4)));

typedef u32 __attribute__((address_space(1))) gu32;
typedef u32 __attribute__((address_space(3))) lu32;

__device__ __forceinline__ u16 f2bf(float f){
  u32 u = __builtin_bit_cast(u32, f);
  u32 r = (u + 0x7fffu + ((u >> 16) & 1u)) >> 16;
  return (u16)r;
}
__device__ __forceinline__ float bf2f(u16 h){
  u32 u = ((u32)h) << 16;
  return __builtin_bit_cast(float, u);
}
__device__ __forceinline__ void gload_lds16(const u16* g, u16* l){
  __builtin_amdgcn_global_load_lds((const gu32*)g, (lu32*)l, 16, 0, 0);
}
__device__ __forceinline__ u32 cvtpk_bf16(float lo, float hi){
  u32 r;
  asm("v_cvt_pk_bf16_f32 %0, %1, %2" : "=v"(r) : "v"(lo), "v"(hi));
  return r;
}

// ---------------- weight f32 -> bf16 ----------------
__global__ __launch_bounds__(256) void conv_w_kernel(
    const float* __restrict__ w0, const float* __restrict__ w1, const float* __restrict__ w2,
    const float* __restrict__ w3, const float* __restrict__ w4, const float* __restrict__ w5,
    u16* __restrict__ o0, u16* __restrict__ o1, u16* __restrict__ o2,
    u16* __restrict__ o3, u16* __restrict__ o4, u16* __restrict__ o5){
  const int i = (blockIdx.x * 256 + threadIdx.x) * 4;
  const float* wsrc[6] = {w0,w1,w2,w3,w4,w5};
  u16* odst[6] = {o0,o1,o2,o3,o4,o5};
#pragma unroll
  for (int k = 0; k < 6; ++k){
    float4 v = *(const float4*)(wsrc[k] + i);
    ushort4 p; p.x=f2bf(v.x); p.y=f2bf(v.y); p.z=f2bf(v.z); p.w=f2bf(v.w);
    *(ushort4*)(odst[k] + i) = p;
  }
}

// ---------------- channel LayerNorm over C per (b,t) row ----------------
template<int OUTBF>
__global__ __launch_bounds__(256) void ln_rows(const float* __restrict__ x,
    const float* __restrict__ g, const float* __restrict__ be, void* __restrict__ out){
  const int row = blockIdx.x, tid = threadIdx.x;
  const float4 v = ((const float4*)(x + (size_t)row * CC))[tid];
  float s  = v.x + v.y + v.z + v.w;
  float ss = v.x*v.x + v.y*v.y + v.z*v.z + v.w*v.w;
  __shared__ float sb[8];
#pragma unroll
  for (int o = 1; o < 64; o <<= 1){ s += __shfl_xor(s, o); ss += __shfl_xor(ss, o); }
  const int wid = tid >> 6, lane = tid & 63;
  if (lane == 0){ sb[wid] = s; sb[4 + wid] = ss; }
  __syncthreads();
  s  = sb[0] + sb[1] + sb[2] + sb[3];
  ss = sb[4] + sb[5] + sb[6] + sb[7];
  const float mu = s * (1.0f / CC);
  const float rstd = rsqrtf(ss * (1.0f / CC) - mu * mu + EPSV);
  const float4 gg = ((const float4*)g)[tid];
  const float4 bb = ((const float4*)be)[tid];
  const float r0 = (v.x - mu) * rstd * gg.x + bb.x;
  const float r1 = (v.y - mu) * rstd * gg.y + bb.y;
  const float r2 = (v.z - mu) * rstd * gg.z + bb.z;
  const float r3 = (v.w - mu) * rstd * gg.w + bb.w;
  if (OUTBF){
    ushort4 p; p.x=f2bf(r0); p.y=f2bf(r1); p.z=f2bf(r2); p.w=f2bf(r3);
    *(ushort4*)((u16*)out + (size_t)row * CC + tid * 4) = p;
  } else {
    ((float4*)((float*)out + (size_t)row * CC))[tid] = make_float4(r0, r1, r2, r3);
  }
}

// ------------ fused q/k/v: dwconv3 (pad1) * mask -> LN -> bf16 ------------
__global__ __launch_bounds__(256) void qkv_pre(const float* __restrict__ h,
    const int* __restrict__ mask,
    const float* __restrict__ qw, const float* __restrict__ kw, const float* __restrict__ vw,
    const float* __restrict__ qg, const float* __restrict__ qb2,
    const float* __restrict__ kg, const float* __restrict__ kb2,
    const float* __restrict__ vg, const float* __restrict__ vb2,
    u16* __restrict__ qn, u16* __restrict__ kn, u16* __restrict__ vn){
  const int row = blockIdx.x, tid = threadIdx.x;
  const int t = row & (TT - 1);
  const float mf = mask[row] ? 1.f : 0.f;
  const float4 z4 = make_float4(0.f, 0.f, 0.f, 0.f);
  const float4 x0 = ((const float4*)(h + (size_t)row * CC))[tid];
  const float4 xm = (t > 0)      ? ((const float4*)(h + (size_t)(row - 1) * CC))[tid] : z4;
  const float4 xp = (t < TT - 1) ? ((const float4*)(h + (size_t)(row + 1) * CC))[tid] : z4;
  const int c = tid * 4;
  const float am[4] = {xm.x, xm.y, xm.z, xm.w};
  const float a0[4] = {x0.x, x0.y, x0.z, x0.w};
  const float ap[4] = {xp.x, xp.y, xp.z, xp.w};
  float yq[4], yk[4], yv[4];
  float sq=0.f, ssq=0.f, sk=0.f, ssk=0.f, sv=0.f, ssv=0.f;
#pragma unroll
  for (int i = 0; i < 4; ++i){
    const float* qwp = qw + (c + i) * 3;
    const float* kwp = kw + (c + i) * 3;
    const float* vwp = vw + (c + i) * 3;
    const float q_ = (am[i]*qwp[0] + a0[i]*qwp[1] + ap[i]*qwp[2]) * mf;
    const float k_ = (am[i]*kwp[0] + a0[i]*kwp[1] + ap[i]*kwp[2]) * mf;
    const float v_ = (am[i]*vwp[0] + a0[i]*vwp[1] + ap[i]*vwp[2]) * mf;
    yq[i]=q_; yk[i]=k_; yv[i]=v_;
    sq+=q_; ssq+=q_*q_; sk+=k_; ssk+=k_*k_; sv+=v_; ssv+=v_*v_;
  }
  __shared__ float sb[24];
#pragma unroll
  for (int o = 1; o < 64; o <<= 1){
    sq += __shfl_xor(sq, o); ssq += __shfl_xor(ssq, o);
    sk += __shfl_xor(sk, o); ssk += __shfl_xor(ssk, o);
    sv += __shfl_xor(sv, o); ssv += __shfl_xor(ssv, o);
  }
  const int wid = tid >> 6, lane = tid & 63;
  if (lane == 0){
    sb[wid]=sq; sb[4+wid]=ssq; sb[8+wid]=sk; sb[12+wid]=ssk; sb[16+wid]=sv; sb[20+wid]=ssv;
  }
  __syncthreads();
  sq  = sb[0]+sb[1]+sb[2]+sb[3];    ssq = sb[4]+sb[5]+sb[6]+sb[7];
  sk  = sb[8]+sb[9]+sb[10]+sb[11];  ssk = sb[12]+sb[13]+sb[14]+sb[15];
  sv  = sb[16]+sb[17]+sb[18]+sb[19];ssv = sb[20]+sb[21]+sb[22]+sb[23];
  {
    const float mu = sq * (1.f/CC), rstd = rsqrtf(ssq*(1.f/CC) - mu*mu + EPSV);
    ushort4 p;
    p.x = f2bf((yq[0]-mu)*rstd*qg[c+0] + qb2[c+0]);
    p.y = f2bf((yq[1]-mu)*rstd*qg[c+1] + qb2[c+1]);
    p.z = f2bf((yq[2]-mu)*rstd*qg[c+2] + qb2[c+2]);
    p.w = f2bf((yq[3]-mu)*rstd*qg[c+3] + qb2[c+3]);
    *(ushort4*)(qn + (size_t)row * CC + c) = p;
  }
  {
    const float mu = sk * (1.f/CC), rstd = rsqrtf(ssk*(1.f/CC) - mu*mu + EPSV);
    ushort4 p;
    p.x = f2bf((yk[0]-mu)*rstd*kg[c+0] + kb2[c+0]);
    p.y = f2bf((yk[1]-mu)*rstd*kg[c+1] + kb2[c+1]);
    p.z = f2bf((yk[2]-mu)*rstd*kg[c+2] + kb2[c+2]);
    p.w = f2bf((yk[3]-mu)*rstd*kg[c+3] + kb2[c+3]);
    *(ushort4*)(kn + (size_t)row * CC + c) = p;
  }
  {
    const float mu = sv * (1.f/CC), rstd = rsqrtf(ssv*(1.f/CC) - mu*mu + EPSV);
    ushort4 p;
    p.x = f2bf((yv[0]-mu)*rstd*vg[c+0] + vb2[c+0]);
    p.y = f2bf((yv[1]-mu)*rstd*vg[c+1] + vb2[c+1]);
    p.z = f2bf((yv[2]-mu)*rstd*vg[c+2] + vb2[c+2]);
    p.w = f2bf((yv[3]-mu)*rstd*vg[c+3] + vb2[c+3]);
    *(ushort4*)(vn + (size_t)row * CC + c) = p;
  }
}

// ---------------- bf16 "bt" GEMM: C[m,n] = sum_k A[m,k]*W[n,k] + bias[n] ----------------
template<int MODE>
__global__ __launch_bounds__(256) void gemm_bt(
    const u16* __restrict__ A, const u16* __restrict__ Bw,
    const float* __restrict__ bias, void* __restrict__ out,
    const float* __restrict__ resid, const int* __restrict__ mask){
  __shared__ u16 As[128 * 32];
  __shared__ u16 Bs[128 * 32];
  const int tid = threadIdx.x, lane = tid & 63, wid = tid >> 6;
  const int wr = wid >> 1, wc = wid & 1;
  const int bm = blockIdx.x, bn = blockIdx.y;
  f32x4 acc[4][4];
#pragma unroll
  for (int i = 0; i < 4; ++i)
#pragma unroll
    for (int j = 0; j < 4; ++j) acc[i][j] = (f32x4){0.f, 0.f, 0.f, 0.f};
  const u16* gA = A  + (size_t)(bm * 128 + wid * 32 + (lane >> 2)) * CC + (lane & 3) * 8;
  const u16* gB = Bw + (size_t)(bn * 128 + wid * 32 + (lane >> 2)) * CC + (lane & 3) * 8;
  u16* lA = &As[wid * 1024];
  u16* lB = &Bs[wid * 1024];
  const int la = lane & 15, lg8 = (lane >> 4) * 8;
  for (int kt = 0; kt < CC / 32; ++kt){
    gload_lds16(gA + kt * 32, lA);
    gload_lds16(gA + kt * 32 + (size_t)16 * CC, lA + 512);
    gload_lds16(gB + kt * 32, lB);
    gload_lds16(gB + kt * 32 + (size_t)16 * CC, lB + 512);
    __syncthreads();
    bf16x8 af[4], bf[4];
#pragma unroll
    for (int mi = 0; mi < 4; ++mi) af[mi] = *(const bf16x8*)&As[(wr*64 + mi*16 + la)*32 + lg8];
#pragma unroll
    for (int ni = 0; ni < 4; ++ni) bf[ni] = *(const bf16x8*)&Bs[(wc*64 + ni*16 + la)*32 + lg8];
#pragma unroll
    for (int mi = 0; mi < 4; ++mi)
#pragma unroll
      for (int ni = 0; ni < 4; ++ni)
        acc[mi][ni] = __builtin_amdgcn_mfma_f32_16x16x32_bf16(af[mi], bf[ni], acc[mi][ni], 0, 0, 0);
    __syncthreads();
  }
  const int lg = lane >> 4;
#pragma unroll
  for (int mi = 0; mi < 4; ++mi){
    const int mb = bm * 128 + wr * 64 + mi * 16 + lg * 4;
#pragma unroll
    for (int ni = 0; ni < 4; ++ni){
      const int n = bn * 128 + wc * 64 + ni * 16 + la;
      const float bz = bias[n];
      if (MODE == 0){
        u16* o = (u16*)out;
#pragma unroll
        for (int j = 0; j < 4; ++j) o[(size_t)(mb + j) * CC + n] = f2bf(acc[mi][ni][j] + bz);
      } else if (MODE == 1){
        float* o = (float*)out;
#pragma unroll
        for (int j = 0; j < 4; ++j){
          const int m = mb + j;
          const float mf = mask[m] ? 1.f : 0.f;
          o[(size_t)m * CC + n] = (acc[mi][ni][j] + bz) * mf + resid[(size_t)m * CC + n];
        }
      } else if (MODE == 2){
        float* o = (float*)out;
#pragma unroll
        for (int j = 0; j < 4; ++j){
          const int m = mb + j;
          o[(size_t)m * CC + n] = acc[mi][ni][j] + bz + resid[(size_t)m * CC + n];
        }
      } else {
        u16* o = (u16*)out;
        const int bq = mb >> 11, tq = mb & (TT - 1);
        const int hq = n >> 8, dq = n & 255;
        ushort4 p;
        p.x = f2bf(acc[mi][ni][0] + bz); p.y = f2bf(acc[mi][ni][1] + bz);
        p.z = f2bf(acc[mi][ni][2] + bz); p.w = f2bf(acc[mi][ni][3] + bz);
        *(ushort4*)&o[(size_t)((bq * HH + hq) * DD + dq) * TT + tq] = p;
      }
    }
  }
}

// ---------------- flash attention v3: S^T swap (q lane-local), KVB=32, 36KB LDS ----------------
// Q,K in (B*T, C) bf16; V pre-transposed to (B,H,D,T) bf16. exp2-domain, defer-max.
__global__ __launch_bounds__(256, 3) void flash_attn(
    const u16* __restrict__ Q, const u16* __restrict__ Kg,
    const u16* __restrict__ Vt, const int* __restrict__ mask,
    u16* __restrict__ Oa){
  __shared__ __align__(16) u16 Ks[32 * 256];   // row k: 512B, swz chunk^=(r&7)
  __shared__ __align__(16) u16 Vs[256 * 32];   // row d: 64B,  swz chunk^=(d&3)
  __shared__ __align__(16) u16 Ps[4][16 * 32]; // per-wave row q: 64B, swz chunk^=(q&3)
  const int qt = blockIdx.x, bh = blockIdx.y;
  const int b = bh >> 2, h2 = bh & 3;
  const int tid = threadIdx.x, lane = tid & 63, wid = tid >> 6;
  const int la = lane & 15, lg = lane >> 4;

  // ---- sequence length via two ballot rounds (prefix mask, len in [1024,2048]) ----
  const int* mrow = mask + b * TT;
  int len = 1024;
  {
    unsigned long long bal = __ballot(mrow[1024 + lane * 16] != 0);
    int ones = __popcll(bal);
    if (ones > 0){
      int lo = 1024 + (ones - 1) * 16;
      unsigned long long bal2 = __ballot(mrow[lo + la] != 0);
      len = lo + __popcll(bal2 & 0xFFFFull);
    }
  }
  const int nkt = (len + 31) >> 5;

  bf16x8 qf[8];
  const u16* qrow = Q + (size_t)(b * TT + qt * 64 + wid * 16 + la) * CC + h2 * DD + lg * 8;
#pragma unroll
  for (int kd = 0; kd < 8; ++kd) qf[kd] = *(const bf16x8*)(qrow + kd * 32);

  f32x4 oacc[16];
#pragma unroll
  for (int i = 0; i < 16; ++i) oacc[i] = (f32x4){0.f, 0.f, 0.f, 0.f};
  float mrun = NEGBIG, lrun = 0.f;

  // staging (pre-swizzled global source, linear LDS dest)
  const int krow = tid >> 5, kchk = tid & 31;
  const u16* ksrc = Kg + (size_t)(b * TT + krow) * CC + h2 * DD + (kchk ^ (krow & 7)) * 8;
  const int vrow = tid >> 2, vchk = tid & 3;
  const u16* vsrc = Vt + (size_t)(bh * DD + vrow) * TT + (vchk ^ (vrow & 3)) * 8;
  u16* kdst = (u16*)((char*)Ks + tid * 16);
  u16* vdst = (u16*)((char*)Vs + tid * 16);

#define STAGE_K(KT) { _Pragma("unroll") \
  for (int i = 0; i < 4; ++i) \
    gload_lds16(ksrc + (size_t)((KT) * 32 + i * 8) * CC, kdst + i * 2048); }
#define STAGE_V(KT) { _Pragma("unroll") \
  for (int i = 0; i < 4; ++i) \
    gload_lds16(vsrc + (size_t)(i * 64) * TT + (KT) * 32, vdst + i * 2048); }

  STAGE_K(0); STAGE_V(0);
  __syncthreads();

  const char* KsB = (const char*)Ks;
  const char* VsB = (const char*)Vs;
  char* PsB = (char*)&Ps[wid][0];
  const int swk = (la & 7) << 4;
  const int swq = (la & 3) << 4;
  const float sc2 = SCALEV * 1.44269504f;   // softmax in exp2 domain

  for (int kt = 0; kt < nkt; ++kt){
    // ---- phase A: S^T = K_tile * Q^T  (lane: q=la, k=fn*16+lg*4+j) ----
    f32x4 sfr[2];
#pragma unroll
    for (int fn = 0; fn < 2; ++fn){
      f32x4 s = (f32x4){0.f, 0.f, 0.f, 0.f};
      const int rk = fn * 16 + la;
#pragma unroll
      for (int kd = 0; kd < 8; ++kd){
        bf16x8 kf = *(const bf16x8*)(KsB + rk * 512 + ((kd * 64 + lg * 16) ^ swk));
        s = __builtin_amdgcn_mfma_f32_16x16x32_bf16(kf, qf[kd], s, 0, 0, 0);
      }
      sfr[fn] = s;
    }
    if (kt * 32 + 32 <= len){
      sfr[0] *= sc2; sfr[1] *= sc2;
    } else {
      const int kb = kt * 32 + lg * 4;
#pragma unroll
      for (int fn = 0; fn < 2; ++fn)
#pragma unroll
        for (int j = 0; j < 4; ++j)
          sfr[fn][j] = (kb + fn * 16 + j < len) ? sfr[fn][j] * sc2 : NEGBIG;
    }
    // ---- online softmax, q = la for all lanes ----
    float tm = fmaxf(fmaxf(fmaxf(sfr[0][0], sfr[0][1]), fmaxf(sfr[0][2], sfr[0][3])),
                     fmaxf(fmaxf(sfr[1][0], sfr[1][1]), fmaxf(sfr[1][2], sfr[1][3])));
    tm = fmaxf(tm, __shfl_xor(tm, 16));
    tm = fmaxf(tm, __shfl_xor(tm, 32));
    if (!__all(tm <= mrun + 12.0f)){   // defer-max: rescale only on real growth
      const float mn = fmaxf(mrun, tm);
      const float al = __builtin_exp2f(mrun - mn);
      mrun = mn; lrun *= al;
#pragma unroll
      for (int i = 0; i < 16; ++i) oacc[i] *= al;
    }
    float p0 = __builtin_exp2f(sfr[0][0] - mrun), p1 = __builtin_exp2f(sfr[0][1] - mrun);
    float p2 = __builtin_exp2f(sfr[0][2] - mrun), p3 = __builtin_exp2f(sfr[0][3] - mrun);
    float p4 = __builtin_exp2f(sfr[1][0] - mrun), p5 = __builtin_exp2f(sfr[1][1] - mrun);
    float p6 = __builtin_exp2f(sfr[1][2] - mrun), p7 = __builtin_exp2f(sfr[1][3] - mrun);
    float ts = ((p0 + p1) + (p2 + p3)) + ((p4 + p5) + (p6 + p7));
    ts += __shfl_xor(ts, 16);
    ts += __shfl_xor(ts, 32);
    lrun += ts;
    {
      uint2 w0; w0.x = cvtpk_bf16(p0, p1); w0.y = cvtpk_bf16(p2, p3);
      uint2 w1; w1.x = cvtpk_bf16(p4, p5); w1.y = cvtpk_bf16(p6, p7);
      *(uint2*)(PsB + la * 64 + ((lg * 8) ^ swq)) = w0;
      *(uint2*)(PsB + la * 64 + ((32 + lg * 8) ^ swq)) = w1;
    }
    __syncthreads();   // b1: Ks readers done; V(kt) drained; Ps visible
    if (kt + 1 < nkt) STAGE_K(kt + 1);   // hides under PV, drained at b2
    // ---- phase B: O^T += V^T_tile * P^T ----
    bf16x8 pf = *(const bf16x8*)(PsB + la * 64 + ((lg * 16) ^ swq));
#pragma unroll
    for (int mi = 0; mi < 16; ++mi){
      const int d = mi * 16 + la;
      bf16x8 vf = *(const bf16x8*)(VsB + d * 64 + ((lg * 16) ^ swq));
      oacc[mi] = __builtin_amdgcn_mfma_f32_16x16x32_bf16(vf, pf, oacc[mi], 0, 0, 0);
    }
    __syncthreads();   // b2: Vs readers done; K(kt+1) drained
    if (kt + 1 < nkt) STAGE_V(kt + 1);   // hides under next QK^T, drained at b1
  }
  // ---- epilogue: lane owns q=la directly ----
  const float inv = 1.f / lrun;
  u16* orow = Oa + (size_t)(b * TT + qt * 64 + wid * 16 + la) * CC + h2 * DD + lg * 4;
#pragma unroll
  for (int mi = 0; mi < 16; ++mi){
    ushort4 p;
    p.x = f2bf(oacc[mi][0] * inv); p.y = f2bf(oacc[mi][1] * inv);
    p.z = f2bf(oacc[mi][2] * inv); p.w = f2bf(oacc[mi][3] * inv);
    *(ushort4*)(orow + mi * 16) = p;
  }
#undef STAGE_K
#undef STAGE_V
}

// ---------------- dwconv(tc) + bias + exact GELU ----------------
__global__ __launch_bounds__(256) void tc_gelu(const u16* __restrict__ y2,
    const float* __restrict__ w, const float* __restrict__ bias, u16* __restrict__ y3){
  const int row = blockIdx.x, tid = threadIdx.x;
  const int t = row & (TT - 1);
  const int c = tid * 4;
  ushort4 z4; z4.x = z4.y = z4.z = z4.w = 0;
  const ushort4 u0 = *(const ushort4*)(y2 + (size_t)row * CC + c);
  const ushort4 um = (t > 0)      ? *(const ushort4*)(y2 + (size_t)(row - 1) * CC + c) : z4;
  const ushort4 up = (t < TT - 1) ? *(const ushort4*)(y2 + (size_t)(row + 1) * CC + c) : z4;
  const float am[4] = {bf2f(um.x), bf2f(um.y), bf2f(um.z), bf2f(um.w)};
  const float a0[4] = {bf2f(u0.x), bf2f(u0.y), bf2f(u0.z), bf2f(u0.w)};
  const float ap[4] = {bf2f(up.x), bf2f(up.y), bf2f(up.z), bf2f(up.w)};
  u16 pv[4];
#pragma unroll
  for (int i = 0; i < 4; ++i){
    const float* wp = w + (c + i) * 3;
    const float yv = am[i] * wp[0] + a0[i] * wp[1] + ap[i] * wp[2] + bias[c + i];
    const float ge = 0.5f * yv * (1.f + erff(yv * 0.7071067811865475f));
    pv[i] = f2bf(ge);
  }
  ushort4 p; p.x = pv[0]; p.y = pv[1]; p.z = pv[2]; p.w = pv[3];
  *(ushort4*)(y3 + (size_t)row * CC + c) = p;
}

extern "C" void kernel_launch(void* const* d_in, const int* in_sizes, int n_in,
                              void* d_out, int out_size, void* d_ws, size_t ws_size,
                              hipStream_t stream){
  const float* x     = (const float*)d_in[0];
  const int*   mask  = (const int*)d_in[1];
  const float* n1g   = (const float*)d_in[2];
  const float* n1b   = (const float*)d_in[3];
  const float* qconv = (const float*)d_in[4];
  const float* kconv = (const float*)d_in[5];
  const float* vconv = (const float*)d_in[6];
  const float* qg    = (const float*)d_in[7];
  const float* qbe   = (const float*)d_in[8];
  const float* kg    = (const float*)d_in[9];
  const float* kbe   = (const float*)d_in[10];
  const float* vg    = (const float*)d_in[11];
  const float* vbe   = (const float*)d_in[12];
  const float* q1w   = (const float*)d_in[13];
  const float* q1b   = (const float*)d_in[14];
  const float* k1w   = (const float*)d_in[15];
  const float* k1b   = (const float*)d_in[16];
  const float* v1w   = (const float*)d_in[17];
  const float* v1b   = (const float*)d_in[18];
  const float* pw    = (const float*)d_in[19];
  const float* pb    = (const float*)d_in[20];
  const float* n2g   = (const float*)d_in[21];
  const float* n2b   = (const float*)d_in[22];
  const float* l1w   = (const float*)d_in[23];
  const float* l1b   = (const float*)d_in[24];
  const float* tcw   = (const float*)d_in[25];
  const float* tcb   = (const float*)d_in[26];
  const float* l2w   = (const float*)d_in[27];
  const float* l2b   = (const float*)d_in[28];
  (void)in_sizes; (void)n_in; (void)out_size; (void)ws_size;

  char* ws = (char*)d_ws;
  const size_t MB = (size_t)1 << 20;
  u16* wq  = (u16*)(ws + 0 * MB);
  u16* wk  = (u16*)(ws + 2 * MB);
  u16* wv  = (u16*)(ws + 4 * MB);
  u16* wp2 = (u16*)(ws + 6 * MB);
  u16* wl1 = (u16*)(ws + 8 * MB);
  u16* wl2 = (u16*)(ws + 10 * MB);
  float* hbuf = (float*)(ws + 12 * MB);   // 32 MB; reused as x2 after attention
  float* x2   = hbuf;
  u16* qn  = (u16*)(ws + 44 * MB);
  u16* kn  = (u16*)(ws + 60 * MB);
  u16* vn  = (u16*)(ws + 76 * MB);
  u16* Qb  = (u16*)(ws + 92 * MB);
  u16* Kb  = (u16*)(ws + 108 * MB);
  u16* Vtb = (u16*)(ws + 124 * MB);
  u16* AO  = qn;    // attnout  (qn dead after q1 GEMM)
  u16* y1  = kn;    // LN2 out  (kn dead after k1 GEMM)
  u16* y2  = vn;    // lin1 out (vn dead after v1 GEMM)
  u16* y3  = Qb;    // gelu out (Q dead after flash)

  conv_w_kernel<<<1024, 256, 0, stream>>>(q1w, k1w, v1w, pw, l1w, l2w, wq, wk, wv, wp2, wl1, wl2);
  ln_rows<0><<<MM, 256, 0, stream>>>(x, n1g, n1b, hbuf);
  qkv_pre<<<MM, 256, 0, stream>>>(hbuf, mask, qconv, kconv, vconv,
                                  qg, qbe, kg, kbe, vg, vbe, qn, kn, vn);
  gemm_bt<0><<<dim3(64, 8), 256, 0, stream>>>(qn, wq, q1b, Qb, nullptr, nullptr);
  gemm_bt<0><<<dim3(64, 8), 256, 0, stream>>>(kn, wk, k1b, Kb, nullptr, nullptr);
  gemm_bt<3><<<dim3(64, 8), 256, 0, stream>>>(vn, wv, v1b, Vtb, nullptr, nullptr);
  flash_attn<<<dim3(32, 16), 256, 0, stream>>>(Qb, Kb, Vtb, mask, AO);
  gemm_bt<1><<<dim3(64, 8), 256, 0, stream>>>(AO, wp2, pb, x2, x, mask);
  ln_rows<1><<<MM, 256, 0, stream>>>(x2, n2g, n2b, y1);
  gemm_bt<0><<<dim3(64, 8), 256, 0, stream>>>(y1, wl1, l1b, y2, nullptr, nullptr);
  tc_gelu<<<MM, 256, 0, stream>>>(y2, tcw, tcb, y3);
  gemm_bt<2><<<dim3(64, 8), 256, 0, stream>>>(y3, wl2, l2b, (float*)d_out, x2, nullptr);
}

// Round 5
// 376.480 us; speedup vs baseline: 1.6053x; 1.0027x over previous
//
#include <hip/hip_runtime.h>

#define BB 4
#define TT 2048
#define CC 1024
#define HH 4
#define DD 256
#define MM (BB*TT)

#define EPSV 1e-5f
#define NEGBIG (-1e30f)
#define SCALEV 0.0625f   // 1/sqrt(256)

typedef unsigned short u16;
typedef unsigned int   u32;
typedef __bf16 bf16x8 __attribute__((ext_vector_type(8)));
typedef float  f32x4  __attribute__((ext_vector_type(4)));

typedef u32 __attribute__((address_space(1))) gu32;
typedef u32 __attribute__((address_space(3))) lu32;

__device__ __forceinline__ u16 f2bf(float f){
  u32 u = __builtin_bit_cast(u32, f);
  u32 r = (u + 0x7fffu + ((u >> 16) & 1u)) >> 16;
  return (u16)r;
}
__device__ __forceinline__ float bf2f(u16 h){
  u32 u = ((u32)h) << 16;
  return __builtin_bit_cast(float, u);
}
__device__ __forceinline__ void gload_lds16(const u16* g, u16* l){
  __builtin_amdgcn_global_load_lds((const gu32*)g, (lu32*)l, 16, 0, 0);
}
__device__ __forceinline__ u32 cvtpk_bf16(float lo, float hi){
  u32 r;
  asm("v_cvt_pk_bf16_f32 %0, %1, %2" : "=v"(r) : "v"(lo), "v"(hi));
  return r;
}

// ---------------- weight f32 -> bf16 ----------------
__global__ __launch_bounds__(256) void conv_w_kernel(
    const float* __restrict__ w0, const float* __restrict__ w1, const float* __restrict__ w2,
    const float* __restrict__ w3, const float* __restrict__ w4, const float* __restrict__ w5,
    u16* __restrict__ o0, u16* __restrict__ o1, u16* __restrict__ o2,
    u16* __restrict__ o3, u16* __restrict__ o4, u16* __restrict__ o5){
  const int i = (blockIdx.x * 256 + threadIdx.x) * 4;
  const float* wsrc[6] = {w0,w1,w2,w3,w4,w5};
  u16* odst[6] = {o0,o1,o2,o3,o4,o5};
#pragma unroll
  for (int k = 0; k < 6; ++k){
    float4 v = *(const float4*)(wsrc[k] + i);
    ushort4 p; p.x=f2bf(v.x); p.y=f2bf(v.y); p.z=f2bf(v.z); p.w=f2bf(v.w);
    *(ushort4*)(odst[k] + i) = p;
  }
}

// ---------------- channel LayerNorm over C per (b,t) row ----------------
template<int OUTBF>
__global__ __launch_bounds__(256) void ln_rows(const float* __restrict__ x,
    const float* __restrict__ g, const float* __restrict__ be, void* __restrict__ out){
  const int row = blockIdx.x, tid = threadIdx.x;
  const float4 v = ((const float4*)(x + (size_t)row * CC))[tid];
  float s  = v.x + v.y + v.z + v.w;
  float ss = v.x*v.x + v.y*v.y + v.z*v.z + v.w*v.w;
  __shared__ float sb[8];
#pragma unroll
  for (int o = 1; o < 64; o <<= 1){ s += __shfl_xor(s, o); ss += __shfl_xor(ss, o); }
  const int wid = tid >> 6, lane = tid & 63;
  if (lane == 0){ sb[wid] = s; sb[4 + wid] = ss; }
  __syncthreads();
  s  = sb[0] + sb[1] + sb[2] + sb[3];
  ss = sb[4] + sb[5] + sb[6] + sb[7];
  const float mu = s * (1.0f / CC);
  const float rstd = rsqrtf(ss * (1.0f / CC) - mu * mu + EPSV);
  const float4 gg = ((const float4*)g)[tid];
  const float4 bb = ((const float4*)be)[tid];
  const float r0 = (v.x - mu) * rstd * gg.x + bb.x;
  const float r1 = (v.y - mu) * rstd * gg.y + bb.y;
  const float r2 = (v.z - mu) * rstd * gg.z + bb.z;
  const float r3 = (v.w - mu) * rstd * gg.w + bb.w;
  if (OUTBF){
    ushort4 p; p.x=f2bf(r0); p.y=f2bf(r1); p.z=f2bf(r2); p.w=f2bf(r3);
    *(ushort4*)((u16*)out + (size_t)row * CC + tid * 4) = p;
  } else {
    ((float4*)((float*)out + (size_t)row * CC))[tid] = make_float4(r0, r1, r2, r3);
  }
}

// ------------ fused q/k/v: dwconv3 (pad1) * mask -> LN -> bf16 ------------
__global__ __launch_bounds__(256) void qkv_pre(const float* __restrict__ h,
    const int* __restrict__ mask,
    const float* __restrict__ qw, const float* __restrict__ kw, const float* __restrict__ vw,
    const float* __restrict__ qg, const float* __restrict__ qb2,
    const float* __restrict__ kg, const float* __restrict__ kb2,
    const float* __restrict__ vg, const float* __restrict__ vb2,
    u16* __restrict__ qn, u16* __restrict__ kn, u16* __restrict__ vn){
  const int row = blockIdx.x, tid = threadIdx.x;
  const int t = row & (TT - 1);
  const float mf = mask[row] ? 1.f : 0.f;
  const float4 z4 = make_float4(0.f, 0.f, 0.f, 0.f);
  const float4 x0 = ((const float4*)(h + (size_t)row * CC))[tid];
  const float4 xm = (t > 0)      ? ((const float4*)(h + (size_t)(row - 1) * CC))[tid] : z4;
  const float4 xp = (t < TT - 1) ? ((const float4*)(h + (size_t)(row + 1) * CC))[tid] : z4;
  const int c = tid * 4;
  const float am[4] = {xm.x, xm.y, xm.z, xm.w};
  const float a0[4] = {x0.x, x0.y, x0.z, x0.w};
  const float ap[4] = {xp.x, xp.y, xp.z, xp.w};
  float yq[4], yk[4], yv[4];
  float sq=0.f, ssq=0.f, sk=0.f, ssk=0.f, sv=0.f, ssv=0.f;
#pragma unroll
  for (int i = 0; i < 4; ++i){
    const float* qwp = qw + (c + i) * 3;
    const float* kwp = kw + (c + i) * 3;
    const float* vwp = vw + (c + i) * 3;
    const float q_ = (am[i]*qwp[0] + a0[i]*qwp[1] + ap[i]*qwp[2]) * mf;
    const float k_ = (am[i]*kwp[0] + a0[i]*kwp[1] + ap[i]*kwp[2]) * mf;
    const float v_ = (am[i]*vwp[0] + a0[i]*vwp[1] + ap[i]*vwp[2]) * mf;
    yq[i]=q_; yk[i]=k_; yv[i]=v_;
    sq+=q_; ssq+=q_*q_; sk+=k_; ssk+=k_*k_; sv+=v_; ssv+=v_*v_;
  }
  __shared__ float sb[24];
#pragma unroll
  for (int o = 1; o < 64; o <<= 1){
    sq += __shfl_xor(sq, o); ssq += __shfl_xor(ssq, o);
    sk += __shfl_xor(sk, o); ssk += __shfl_xor(ssk, o);
    sv += __shfl_xor(sv, o); ssv += __shfl_xor(ssv, o);
  }
  const int wid = tid >> 6, lane = tid & 63;
  if (lane == 0){
    sb[wid]=sq; sb[4+wid]=ssq; sb[8+wid]=sk; sb[12+wid]=ssk; sb[16+wid]=sv; sb[20+wid]=ssv;
  }
  __syncthreads();
  sq  = sb[0]+sb[1]+sb[2]+sb[3];    ssq = sb[4]+sb[5]+sb[6]+sb[7];
  sk  = sb[8]+sb[9]+sb[10]+sb[11];  ssk = sb[12]+sb[13]+sb[14]+sb[15];
  sv  = sb[16]+sb[17]+sb[18]+sb[19];ssv = sb[20]+sb[21]+sb[22]+sb[23];
  {
    const float mu = sq * (1.f/CC), rstd = rsqrtf(ssq*(1.f/CC) - mu*mu + EPSV);
    ushort4 p;
    p.x = f2bf((yq[0]-mu)*rstd*qg[c+0] + qb2[c+0]);
    p.y = f2bf((yq[1]-mu)*rstd*qg[c+1] + qb2[c+1]);
    p.z = f2bf((yq[2]-mu)*rstd*qg[c+2] + qb2[c+2]);
    p.w = f2bf((yq[3]-mu)*rstd*qg[c+3] + qb2[c+3]);
    *(ushort4*)(qn + (size_t)row * CC + c) = p;
  }
  {
    const float mu = sk * (1.f/CC), rstd = rsqrtf(ssk*(1.f/CC) - mu*mu + EPSV);
    ushort4 p;
    p.x = f2bf((yk[0]-mu)*rstd*kg[c+0] + kb2[c+0]);
    p.y = f2bf((yk[1]-mu)*rstd*kg[c+1] + kb2[c+1]);
    p.z = f2bf((yk[2]-mu)*rstd*kg[c+2] + kb2[c+2]);
    p.w = f2bf((yk[3]-mu)*rstd*kg[c+3] + kb2[c+3]);
    *(ushort4*)(kn + (size_t)row * CC + c) = p;
  }
  {
    const float mu = sv * (1.f/CC), rstd = rsqrtf(ssv*(1.f/CC) - mu*mu + EPSV);
    ushort4 p;
    p.x = f2bf((yv[0]-mu)*rstd*vg[c+0] + vb2[c+0]);
    p.y = f2bf((yv[1]-mu)*rstd*vg[c+1] + vb2[c+1]);
    p.z = f2bf((yv[2]-mu)*rstd*vg[c+2] + vb2[c+2]);
    p.w = f2bf((yv[3]-mu)*rstd*vg[c+3] + vb2[c+3]);
    *(ushort4*)(vn + (size_t)row * CC + c) = p;
  }
}

// ---------------- bf16 "bt" GEMM: C[m,n] = sum_k A[m,k]*W[n,k] + bias[n] ----------------
template<int MODE>
__global__ __launch_bounds__(256) void gemm_bt(
    const u16* __restrict__ A, const u16* __restrict__ Bw,
    const float* __restrict__ bias, void* __restrict__ out,
    const float* __restrict__ resid, const int* __restrict__ mask){
  __shared__ u16 As[128 * 32];
  __shared__ u16 Bs[128 * 32];
  const int tid = threadIdx.x, lane = tid & 63, wid = tid >> 6;
  const int wr = wid >> 1, wc = wid & 1;
  const int bm = blockIdx.x, bn = blockIdx.y;
  f32x4 acc[4][4];
#pragma unroll
  for (int i = 0; i < 4; ++i)
#pragma unroll
    for (int j = 0; j < 4; ++j) acc[i][j] = (f32x4){0.f, 0.f, 0.f, 0.f};
  const u16* gA = A  + (size_t)(bm * 128 + wid * 32 + (lane >> 2)) * CC + (lane & 3) * 8;
  const u16* gB = Bw + (size_t)(bn * 128 + wid * 32 + (lane >> 2)) * CC + (lane & 3) * 8;
  u16* lA = &As[wid * 1024];
  u16* lB = &Bs[wid * 1024];
  const int la = lane & 15, lg8 = (lane >> 4) * 8;
  for (int kt = 0; kt < CC / 32; ++kt){
    gload_lds16(gA + kt * 32, lA);
    gload_lds16(gA + kt * 32 + (size_t)16 * CC, lA + 512);
    gload_lds16(gB + kt * 32, lB);
    gload_lds16(gB + kt * 32 + (size_t)16 * CC, lB + 512);
    __syncthreads();
    bf16x8 af[4], bf[4];
#pragma unroll
    for (int mi = 0; mi < 4; ++mi) af[mi] = *(const bf16x8*)&As[(wr*64 + mi*16 + la)*32 + lg8];
#pragma unroll
    for (int ni = 0; ni < 4; ++ni) bf[ni] = *(const bf16x8*)&Bs[(wc*64 + ni*16 + la)*32 + lg8];
#pragma unroll
    for (int mi = 0; mi < 4; ++mi)
#pragma unroll
      for (int ni = 0; ni < 4; ++ni)
        acc[mi][ni] = __builtin_amdgcn_mfma_f32_16x16x32_bf16(af[mi], bf[ni], acc[mi][ni], 0, 0, 0);
    __syncthreads();
  }
  const int lg = lane >> 4;
#pragma unroll
  for (int mi = 0; mi < 4; ++mi){
    const int mb = bm * 128 + wr * 64 + mi * 16 + lg * 4;
#pragma unroll
    for (int ni = 0; ni < 4; ++ni){
      const int n = bn * 128 + wc * 64 + ni * 16 + la;
      const float bz = bias[n];
      if (MODE == 0){
        u16* o = (u16*)out;
#pragma unroll
        for (int j = 0; j < 4; ++j) o[(size_t)(mb + j) * CC + n] = f2bf(acc[mi][ni][j] + bz);
      } else if (MODE == 1){
        float* o = (float*)out;
#pragma unroll
        for (int j = 0; j < 4; ++j){
          const int m = mb + j;
          const float mf = mask[m] ? 1.f : 0.f;
          o[(size_t)m * CC + n] = (acc[mi][ni][j] + bz) * mf + resid[(size_t)m * CC + n];
        }
      } else if (MODE == 2){
        float* o = (float*)out;
#pragma unroll
        for (int j = 0; j < 4; ++j){
          const int m = mb + j;
          o[(size_t)m * CC + n] = acc[mi][ni][j] + bz + resid[(size_t)m * CC + n];
        }
      } else {
        u16* o = (u16*)out;
        const int bq = mb >> 11, tq = mb & (TT - 1);
        const int hq = n >> 8, dq = n & 255;
        ushort4 p;
        p.x = f2bf(acc[mi][ni][0] + bz); p.y = f2bf(acc[mi][ni][1] + bz);
        p.z = f2bf(acc[mi][ni][2] + bz); p.w = f2bf(acc[mi][ni][3] + bz);
        *(ushort4*)&o[(size_t)((bq * HH + hq) * DD + dq) * TT + tq] = p;
      }
    }
  }
}

// ---------------- flash attention v4: 80B-stride V/P (2-way banks), K/V dbuf, 1 barrier/tile ----------------
// Q,K in (B*T, C) bf16; V pre-transposed to (B,H,D,T) bf16. exp2-domain, defer-max.
__global__ __launch_bounds__(256, 2) void flash_attn(
    const u16* __restrict__ Q, const u16* __restrict__ Kg,
    const u16* __restrict__ Vt, const int* __restrict__ mask,
    u16* __restrict__ Oa){
  __shared__ __align__(16) u16 Ks[2][32 * 256];   // 16KB/buf; row k: 512B, swz chunk^=(r&7)
  __shared__ __align__(16) u16 Vs[2][1280 * 8];   // 20KB/buf; row d: 80B (5 granules, last pad)
  __shared__ __align__(16) u16 Ps[4][640];        // per-wave 16 q x 80B
  // XCD partition: block D -> XCD D%8; XCD x owns bh in {2x, 2x+1} (4MB K/V = its L2)
  const int Dn = blockIdx.x;
  const int bh = (Dn & 7) * 2 + ((Dn >> 3) >> 5);
  const int qt = (Dn >> 3) & 31;
  const int b = bh >> 2, h2 = bh & 3;
  const int tid = threadIdx.x, lane = tid & 63, wid = tid >> 6;
  const int la = lane & 15, lg = lane >> 4;

  // ---- sequence length via two ballot rounds (prefix mask, len in [1024,2048]) ----
  const int* mrow = mask + b * TT;
  int len = 1024;
  {
    unsigned long long bal = __ballot(mrow[1024 + lane * 16] != 0);
    int ones = __popcll(bal);
    if (ones > 0){
      int lo = 1024 + (ones - 1) * 16;
      unsigned long long bal2 = __ballot(mrow[lo + la] != 0);
      len = lo + __popcll(bal2 & 0xFFFFull);
    }
  }
  const int nkt = (len + 31) >> 5;

  bf16x8 qf[8];
  const u16* qrow = Q + (size_t)(b * TT + qt * 64 + wid * 16 + la) * CC + h2 * DD + lg * 8;
#pragma unroll
  for (int kd = 0; kd < 8; ++kd) qf[kd] = *(const bf16x8*)(qrow + kd * 32);

  f32x4 oacc[16];
#pragma unroll
  for (int i = 0; i < 16; ++i) oacc[i] = (f32x4){0.f, 0.f, 0.f, 0.f};
  float mrun = NEGBIG, lrun = 0.f;

  // staging (pre-swizzled global source for K; linear LDS dest, wave-uniform base)
  const int krow = tid >> 5, kchk = tid & 31;
  const u16* ksrc = Kg + (size_t)(b * TT + krow) * CC + h2 * DD + (kchk ^ (krow & 7)) * 8;
  u16* KsW = &Ks[0][0];
  u16* VsW = &Vs[0][0];

  auto stageK = [&](int KT, int BUF){
#pragma unroll
    for (int i = 0; i < 4; ++i)
      gload_lds16(ksrc + (size_t)(KT * 32 + i * 8) * CC,
                  KsW + BUF * 8192 + i * 2048 + wid * 512);
  };
  auto stageV = [&](int KT, int BUF){
#pragma unroll
    for (int i = 0; i < 5; ++i){
      const int g = i * 256 + tid;
      const int dd = g / 5, cc = g % 5;   // granule -> (d row, 16B chunk); cc==4 is pad
      if (cc < 4)
        gload_lds16(Vt + (size_t)(bh * DD + dd) * TT + KT * 32 + cc * 8,
                    VsW + BUF * 10240 + i * 2048 + wid * 512);
    }
  };

  stageK(0, 0); stageV(0, 0);
  __syncthreads();

  char* PsB = (char*)&Ps[wid][0];
  const int swk = (la & 7) << 4;
  const float sc2 = SCALEV * 1.44269504f;   // softmax in exp2 domain

  for (int kt = 0; kt < nkt; ++kt){
    const int cur = kt & 1;
    // issue next-tile stages first: drain at this tile's end barrier (full-tile latency window)
    if (kt + 1 < nkt){ stageK(kt + 1, cur ^ 1); stageV(kt + 1, cur ^ 1); }
    const char* KsB = (const char*)&Ks[cur][0];
    const char* VsB = (const char*)&Vs[cur][0];
    // ---- phase A: S^T = K_tile * Q^T  (lane: q=la, k=fn*16+lg*4+j) ----
    f32x4 sfr[2];
#pragma unroll
    for (int fn = 0; fn < 2; ++fn){
      f32x4 s = (f32x4){0.f, 0.f, 0.f, 0.f};
      const int rk = fn * 16 + la;
#pragma unroll
      for (int kd = 0; kd < 8; ++kd){
        bf16x8 kf = *(const bf16x8*)(KsB + rk * 512 + ((kd * 64 + lg * 16) ^ swk));
        s = __builtin_amdgcn_mfma_f32_16x16x32_bf16(kf, qf[kd], s, 0, 0, 0);
      }
      sfr[fn] = s;
    }
    if (kt * 32 + 32 <= len){
      sfr[0] *= sc2; sfr[1] *= sc2;
    } else {
      const int kb = kt * 32 + lg * 4;
#pragma unroll
      for (int fn = 0; fn < 2; ++fn)
#pragma unroll
        for (int j = 0; j < 4; ++j)
          sfr[fn][j] = (kb + fn * 16 + j < len) ? sfr[fn][j] * sc2 : NEGBIG;
    }
    // ---- online softmax, q = la for all lanes ----
    float tm = fmaxf(fmaxf(fmaxf(sfr[0][0], sfr[0][1]), fmaxf(sfr[0][2], sfr[0][3])),
                     fmaxf(fmaxf(sfr[1][0], sfr[1][1]), fmaxf(sfr[1][2], sfr[1][3])));
    tm = fmaxf(tm, __shfl_xor(tm, 16));
    tm = fmaxf(tm, __shfl_xor(tm, 32));
    if (!__all(tm <= mrun + 12.0f)){   // defer-max: rescale only on real growth
      const float mn = fmaxf(mrun, tm);
      const float al = __builtin_exp2f(mrun - mn);
      mrun = mn; lrun *= al;
#pragma unroll
      for (int i = 0; i < 16; ++i) oacc[i] *= al;
    }
    float p0 = __builtin_exp2f(sfr[0][0] - mrun), p1 = __builtin_exp2f(sfr[0][1] - mrun);
    float p2 = __builtin_exp2f(sfr[0][2] - mrun), p3 = __builtin_exp2f(sfr[0][3] - mrun);
    float p4 = __builtin_exp2f(sfr[1][0] - mrun), p5 = __builtin_exp2f(sfr[1][1] - mrun);
    float p6 = __builtin_exp2f(sfr[1][2] - mrun), p7 = __builtin_exp2f(sfr[1][3] - mrun);
    float ts = ((p0 + p1) + (p2 + p3)) + ((p4 + p5) + (p6 + p7));
    ts += __shfl_xor(ts, 16);
    ts += __shfl_xor(ts, 32);
    lrun += ts;
    {
      uint2 w0; w0.x = cvtpk_bf16(p0, p1); w0.y = cvtpk_bf16(p2, p3);
      uint2 w1; w1.x = cvtpk_bf16(p4, p5); w1.y = cvtpk_bf16(p6, p7);
      *(uint2*)(PsB + la * 80 + lg * 8) = w0;         // k = lg*4 .. +3
      *(uint2*)(PsB + la * 80 + 32 + lg * 8) = w1;    // k = 16 + lg*4 .. +3
    }
    // ---- phase B: O^T += V^T_tile * P^T (Ps wave-private: compiler-ordered, no barrier) ----
    bf16x8 pf = *(const bf16x8*)(PsB + la * 80 + lg * 16);
#pragma unroll
    for (int mi = 0; mi < 16; ++mi){
      bf16x8 vf = *(const bf16x8*)(VsB + (mi * 16 + la) * 80 + lg * 16);
      oacc[mi] = __builtin_amdgcn_mfma_f32_16x16x32_bf16(vf, pf, oacc[mi], 0, 0, 0);
    }
    __syncthreads();   // readers of buf[cur] done; stages into buf[cur^1] drained
  }
  // ---- epilogue: lane owns q=la directly ----
  const float inv = 1.f / lrun;
  u16* orow = Oa + (size_t)(b * TT + qt * 64 + wid * 16 + la) * CC + h2 * DD + lg * 4;
#pragma unroll
  for (int mi = 0; mi < 16; ++mi){
    ushort4 p;
    p.x = f2bf(oacc[mi][0] * inv); p.y = f2bf(oacc[mi][1] * inv);
    p.z = f2bf(oacc[mi][2] * inv); p.w = f2bf(oacc[mi][3] * inv);
    *(ushort4*)(orow + mi * 16) = p;
  }
}

// ---------------- dwconv(tc) + bias + exact GELU ----------------
__global__ __launch_bounds__(256) void tc_gelu(const u16* __restrict__ y2,
    const float* __restrict__ w, const float* __restrict__ bias, u16* __restrict__ y3){
  const int row = blockIdx.x, tid = threadIdx.x;
  const int t = row & (TT - 1);
  const int c = tid * 4;
  ushort4 z4; z4.x = z4.y = z4.z = z4.w = 0;
  const ushort4 u0 = *(const ushort4*)(y2 + (size_t)row * CC + c);
  const ushort4 um = (t > 0)      ? *(const ushort4*)(y2 + (size_t)(row - 1) * CC + c) : z4;
  const ushort4 up = (t < TT - 1) ? *(const ushort4*)(y2 + (size_t)(row + 1) * CC + c) : z4;
  const float am[4] = {bf2f(um.x), bf2f(um.y), bf2f(um.z), bf2f(um.w)};
  const float a0[4] = {bf2f(u0.x), bf2f(u0.y), bf2f(u0.z), bf2f(u0.w)};
  const float ap[4] = {bf2f(up.x), bf2f(up.y), bf2f(up.z), bf2f(up.w)};
  u16 pv[4];
#pragma unroll
  for (int i = 0; i < 4; ++i){
    const float* wp = w + (c + i) * 3;
    const float yv = am[i] * wp[0] + a0[i] * wp[1] + ap[i] * wp[2] + bias[c + i];
    const float ge = 0.5f * yv * (1.f + erff(yv * 0.7071067811865475f));
    pv[i] = f2bf(ge);
  }
  ushort4 p; p.x = pv[0]; p.y = pv[1]; p.z = pv[2]; p.w = pv[3];
  *(ushort4*)(y3 + (size_t)row * CC + c) = p;
}

extern "C" void kernel_launch(void* const* d_in, const int* in_sizes, int n_in,
                              void* d_out, int out_size, void* d_ws, size_t ws_size,
                              hipStream_t stream){
  const float* x     = (const float*)d_in[0];
  const int*   mask  = (const int*)d_in[1];
  const float* n1g   = (const float*)d_in[2];
  const float* n1b   = (const float*)d_in[3];
  const float* qconv = (const float*)d_in[4];
  const float* kconv = (const float*)d_in[5];
  const float* vconv = (const float*)d_in[6];
  const float* qg    = (const float*)d_in[7];
  const float* qbe   = (const float*)d_in[8];
  const float* kg    = (const float*)d_in[9];
  const float* kbe   = (const float*)d_in[10];
  const float* vg    = (const float*)d_in[11];
  const float* vbe   = (const float*)d_in[12];
  const float* q1w   = (const float*)d_in[13];
  const float* q1b   = (const float*)d_in[14];
  const float* k1w   = (const float*)d_in[15];
  const float* k1b   = (const float*)d_in[16];
  const float* v1w   = (const float*)d_in[17];
  const float* v1b   = (const float*)d_in[18];
  const float* pw    = (const float*)d_in[19];
  const float* pb    = (const float*)d_in[20];
  const float* n2g   = (const float*)d_in[21];
  const float* n2b   = (const float*)d_in[22];
  const float* l1w   = (const float*)d_in[23];
  const float* l1b   = (const float*)d_in[24];
  const float* tcw   = (const float*)d_in[25];
  const float* tcb   = (const float*)d_in[26];
  const float* l2w   = (const float*)d_in[27];
  const float* l2b   = (const float*)d_in[28];
  (void)in_sizes; (void)n_in; (void)out_size; (void)ws_size;

  char* ws = (char*)d_ws;
  const size_t MB = (size_t)1 << 20;
  u16* wq  = (u16*)(ws + 0 * MB);
  u16* wk  = (u16*)(ws + 2 * MB);
  u16* wv  = (u16*)(ws + 4 * MB);
  u16* wp2 = (u16*)(ws + 6 * MB);
  u16* wl1 = (u16*)(ws + 8 * MB);
  u16* wl2 = (u16*)(ws + 10 * MB);
  float* hbuf = (float*)(ws + 12 * MB);   // 32 MB; reused as x2 after attention
  float* x2   = hbuf;
  u16* qn  = (u16*)(ws + 44 * MB);
  u16* kn  = (u16*)(ws + 60 * MB);
  u16* vn  = (u16*)(ws + 76 * MB);
  u16* Qb  = (u16*)(ws + 92 * MB);
  u16* Kb  = (u16*)(ws + 108 * MB);
  u16* Vtb = (u16*)(ws + 124 * MB);
  u16* AO  = qn;    // attnout  (qn dead after q1 GEMM)
  u16* y1  = kn;    // LN2 out  (kn dead after k1 GEMM)
  u16* y2  = vn;    // lin1 out (vn dead after v1 GEMM)
  u16* y3  = Qb;    // gelu out (Q dead after flash)

  conv_w_kernel<<<1024, 256, 0, stream>>>(q1w, k1w, v1w, pw, l1w, l2w, wq, wk, wv, wp2, wl1, wl2);
  ln_rows<0><<<MM, 256, 0, stream>>>(x, n1g, n1b, hbuf);
  qkv_pre<<<MM, 256, 0, stream>>>(hbuf, mask, qconv, kconv, vconv,
                                  qg, qbe, kg, kbe, vg, vbe, qn, kn, vn);
  gemm_bt<0><<<dim3(64, 8), 256, 0, stream>>>(qn, wq, q1b, Qb, nullptr, nullptr);
  gemm_bt<0><<<dim3(64, 8), 256, 0, stream>>>(kn, wk, k1b, Kb, nullptr, nullptr);
  gemm_bt<3><<<dim3(64, 8), 256, 0, stream>>>(vn, wv, v1b, Vtb, nullptr, nullptr);
  flash_attn<<<512, 256, 0, stream>>>(Qb, Kb, Vtb, mask, AO);
  gemm_bt<1><<<dim3(64, 8), 256, 0, stream>>>(AO, wp2, pb, x2, x, mask);
  ln_rows<1><<<MM, 256, 0, stream>>>(x2, n2g, n2b, y1);
  gemm_bt<0><<<dim3(64, 8), 256, 0, stream>>>(y1, wl1, l1b, y2, nullptr, nullptr);
  tc_gelu<<<MM, 256, 0, stream>>>(y2, tcw, tcb, y3);
  gemm_bt<2><<<dim3(64, 8), 256, 0, stream>>>(y3, wl2, l2b, (float*)d_out, x2, nullptr);
}